// Round 4
// baseline (2752.440 us; speedup 1.0000x reference)
//
#include <hip/hip_runtime.h>

#define N_ 4096
#define M_ 10
#define T_ 10
#define B_ 1024
#define P_ 1024
#define AD_ 64
#define NBLK 256

__device__ __forceinline__ float wave_red_sum(float v) {
#pragma unroll
  for (int m = 32; m >= 1; m >>= 1) v += __shfl_xor(v, m);
  return v;
}

// Hand-rolled grid barrier: device-scope atomics, sense-reversing via generation
// counter. All NBLK blocks guaranteed co-resident (256 blocks x 256 thr on 256 CUs).
__device__ __forceinline__ void gridbar(unsigned* cnt, unsigned* gen) {
  __syncthreads();
  if (threadIdx.x == 0) {
    __threadfence();  // release: flush my writes to device scope
    unsigned g = __hip_atomic_load(gen, __ATOMIC_RELAXED, __HIP_MEMORY_SCOPE_AGENT);
    unsigned a = __hip_atomic_fetch_add(cnt, 1u, __ATOMIC_ACQ_REL, __HIP_MEMORY_SCOPE_AGENT);
    if (a == NBLK - 1) {
      __hip_atomic_store(cnt, 0u, __ATOMIC_RELAXED, __HIP_MEMORY_SCOPE_AGENT);
      __hip_atomic_store(gen, g + 1u, __ATOMIC_RELEASE, __HIP_MEMORY_SCOPE_AGENT);
    } else {
      while (__hip_atomic_load(gen, __ATOMIC_ACQUIRE, __HIP_MEMORY_SCOPE_AGENT) == g) {
        __builtin_amdgcn_s_sleep(1);
      }
    }
    __threadfence();  // acquire side: invalidate so fresh data is visible
  }
  __syncthreads();
}

// Copy state, extract post_last, zero barrier counters. 256 blocks x 256.
__global__ __launch_bounds__(256)
void k_init(const float* __restrict__ post0, const float* __restrict__ pre0,
            float* __restrict__ post, float* __restrict__ pre,
            float* __restrict__ post_last, unsigned* __restrict__ bar) {
  int i = blockIdx.x * 256 + threadIdx.x;
  if (i < N_ * M_) { post[i] = post0[i]; pre[i] = pre0[i]; }
  if (i < N_) post_last[i] = post0[i * M_ + (M_ - 1)];
  if (i == 0) { bar[0] = 0u; bar[1] = 0u; }
}

// Fused encoder: 512 blocks x 256 threads; 2 batch rows/block, 2-way k-split.
__global__ __launch_bounds__(256)
void k_enc(const float* __restrict__ x,
           const float* __restrict__ w1, const float* __restrict__ b1,
           const float* __restrict__ g1, const float* __restrict__ be1,
           const float* __restrict__ w2, const float* __restrict__ b2,
           const float* __restrict__ g2, const float* __restrict__ be2,
           const float* __restrict__ w3, const float* __restrict__ b3,
           const float* __restrict__ vw, const float* __restrict__ vb,
           float* __restrict__ enc_g, float* __restrict__ values_g) {
  const int tid = threadIdx.x;
  const int b0 = blockIdx.x * 2;
  const int kh = tid >> 7, j = tid & 127;
  __shared__ float fx[2][784];
  __shared__ float sp[2][2][128];
  __shared__ float e1[2][128];
  __shared__ float e2[2][32];
  __shared__ float encs[2][4];
  __shared__ float red[2][2][2];

  for (int i = tid; i < 2 * 784; i += 256) {
    int r = i / 784, k = i - r * 784;
    fx[r][k] = x[(b0 + r) * 784 + k];
  }
  __syncthreads();

  float a0 = 0.f, a1 = 0.f;
  const int kbeg = kh * 392;
#pragma unroll 4
  for (int k = kbeg; k < kbeg + 392; ++k) {
    float w = w1[k * 128 + j];
    a0 += fx[0][k] * w;
    a1 += fx[1][k] * w;
  }
  sp[kh][0][j] = a0;
  sp[kh][1][j] = a1;
  __syncthreads();

  float acc0 = 0.f, acc1 = 0.f;
  if (kh == 0) {
    float bb = b1[j];
    acc0 = sp[0][0][j] + sp[1][0][j] + bb;
    acc1 = sp[0][1][j] + sp[1][1][j] + bb;
    int wid = j >> 6;
    float s0 = wave_red_sum(acc0), q0 = wave_red_sum(acc0 * acc0);
    float s1 = wave_red_sum(acc1), q1 = wave_red_sum(acc1 * acc1);
    if ((j & 63) == 0) {
      red[wid][0][0] = s0; red[wid][0][1] = q0;
      red[wid][1][0] = s1; red[wid][1][1] = q1;
    }
  }
  __syncthreads();
  if (kh == 0) {
    float gg = g1[j], bbe = be1[j];
    float S0 = red[0][0][0] + red[1][0][0], Q0 = red[0][0][1] + red[1][0][1];
    float S1 = red[0][1][0] + red[1][1][0], Q1 = red[0][1][1] + red[1][1][1];
    float m0 = S0 * (1.f / 128.f), v0 = Q0 * (1.f / 128.f) - m0 * m0;
    float m1 = S1 * (1.f / 128.f), v1 = Q1 * (1.f / 128.f) - m1 * m1;
    e1[0][j] = fmaxf((acc0 - m0) * rsqrtf(v0 + 1e-5f) * gg + bbe, 0.f);
    e1[1][j] = fmaxf((acc1 - m1) * rsqrtf(v1 + 1e-5f) * gg + bbe, 0.f);
  }
  __syncthreads();

  if (tid < 64) {
    int r = tid >> 5, jj = tid & 31;
    float u = b2[jj];
    for (int k = 0; k < 128; ++k) u += e1[r][k] * w2[k * 32 + jj];
    float ss = u, ss2 = u * u;
#pragma unroll
    for (int m = 16; m >= 1; m >>= 1) { ss += __shfl_xor(ss, m, 32); ss2 += __shfl_xor(ss2, m, 32); }
    float mm = ss * (1.f / 32.f), vv = ss2 * (1.f / 32.f) - mm * mm;
    e2[r][jj] = fmaxf((u - mm) * rsqrtf(vv + 1e-5f) * g2[jj] + be2[jj], 0.f);
  }
  __syncthreads();

  if (tid < 8) {
    int r = tid >> 2, o = tid & 3;
    float u = b3[o];
    for (int k = 0; k < 32; ++k) u += e2[r][k] * w3[k * 4 + o];
    encs[r][o] = u;
    enc_g[(b0 + r) * 4 + o] = u;
  }
  __syncthreads();

  if (tid < 128) {  // values; softmax over size-1 axis == 1 -> att == values
    int r = tid >> 6, v = tid & 63;
    float u = vb[v];
#pragma unroll
    for (int o = 0; o < 4; ++o) u += encs[r][o] * vw[o * 64 + v];
    values_g[(b0 + r) * 64 + v] = u;
  }
}

struct PersistArgs {
  const float *enc, *syw1, *syb1, *syg, *sybe, *syw2, *syb2;
  const float *nw1, *nb1, *ng, *nbe, *nw2, *nb2;
  const int* pairs;
  const float* decay;
  const float *rdw1, *rdb1;
  float *post, *pre, *post_last, *c_part, *hb_part, *syncv, *sc_part, *sc;
  unsigned* bar;
};

// Persistent kernel: whole T=10 recurrence + sync + sc. 256 blocks x 256 threads.
__global__ __launch_bounds__(256)
void k_persist(PersistArgs a) {
  const int g = blockIdx.x, tid = threadIdx.x;
  const int wid = tid >> 6, lane = tid & 63;
  unsigned* cnt = a.bar;
  unsigned* gen = a.bar + 1;
  __shared__ float s_pl[64];
  __shared__ float s_encl[8][4];
  __shared__ float s_red[8];
  __shared__ float s_hbar[256];
  __shared__ float s_part[16][16];
  __shared__ float s_pre[16][10];
  __shared__ float s_sv[16];

  for (int t = 0; t < T_; ++t) {
    // ---- P1: c_part[64][256] — block g<64 covers n in [64g, 64g+64) ----
    if (g < 64) {
      if (tid < 64) s_pl[tid] = a.post_last[g * 64 + tid];
      __syncthreads();
      float acc = 0.f;
#pragma unroll 8
      for (int i = 0; i < 64; ++i)
        acc += s_pl[i] * a.syw1[(4 + g * 64 + i) * 256 + tid];
      a.c_part[g * 256 + tid] = acc;
    }
    gridbar(cnt, gen);

    // ---- P2: blocks g<128, 8 batch rows each -> hb_part[g][256] ----
    if (g < 128) {
      int b0 = g * 8;
      float cj = a.syb1[tid];
#pragma unroll 8
      for (int r = 0; r < 64; ++r) cj += a.c_part[r * 256 + tid];
      float w4[4];
#pragma unroll
      for (int o = 0; o < 4; ++o) w4[o] = a.syw1[o * 256 + tid];
      if (tid < 32) s_encl[tid >> 2][tid & 3] = a.enc[(b0 + (tid >> 2)) * 4 + (tid & 3)];
      __syncthreads();
      float gg = a.syg[tid], bb = a.sybe[tid];
      float hacc = 0.f;
#pragma unroll
      for (int rr = 0; rr < 8; ++rr) {
        float u = cj;
#pragma unroll
        for (int o = 0; o < 4; ++o) u += s_encl[rr][o] * w4[o];
        float s = wave_red_sum(u), s2 = wave_red_sum(u * u);
        if (lane == 0) { s_red[wid * 2] = s; s_red[wid * 2 + 1] = s2; }
        __syncthreads();
        float S = s_red[0] + s_red[2] + s_red[4] + s_red[6];
        float S2 = s_red[1] + s_red[3] + s_red[5] + s_red[7];
        float m = S * (1.f / 256.f), v = S2 * (1.f / 256.f) - m * m;
        hacc += fmaxf((u - m) * rsqrtf(v + 1e-5f) * gg + bb, 0.f);
        __syncthreads();
      }
      a.hb_part[g * 256 + tid] = hacc;
    }
    gridbar(cnt, gen);

    // ---- P3: all 256 blocks, 16 n each: hbar, pre shift, nm, post shift ----
    {
      int n0 = g * 16;
      float acc = 0.f;
#pragma unroll 8
      for (int r = 0; r < 128; ++r) acc += a.hb_part[r * 256 + tid];
      s_hbar[tid] = acc * (1.f / 1024.f);
      __syncthreads();
      int kq = tid >> 4, nl = tid & 15;
      {
        float u = 0.f;
#pragma unroll
        for (int kk = 0; kk < 16; ++kk) {
          int k = kq * 16 + kk;
          u += s_hbar[k] * a.syw2[k * N_ + n0 + nl];
        }
        s_part[kq][nl] = u;
      }
      __syncthreads();
      if (tid < 16) {
        int n2 = n0 + tid;
        float v = a.syb2[n2];
#pragma unroll
        for (int q = 0; q < 16; ++q) v += s_part[q][tid];
        float row[M_];
#pragma unroll
        for (int m = 0; m < M_ - 1; ++m) row[m] = a.pre[n2 * M_ + m + 1];
        row[M_ - 1] = v;
#pragma unroll
        for (int m = 0; m < M_; ++m) { a.pre[n2 * M_ + m] = row[m]; s_pre[tid][m] = row[m]; }
      }
      __syncthreads();
      int grp = tid >> 7, jj = tid & 127;
#pragma unroll
      for (int it = 0; it < 8; ++it) {
        int nl2 = it * 2 + grp;
        int n2 = n0 + nl2;
        float u2 = a.nb1[n2 * 128 + jj];
#pragma unroll
        for (int m = 0; m < M_; ++m) u2 += s_pre[nl2][m] * a.nw1[(n2 * M_ + m) * 128 + jj];
        float s = wave_red_sum(u2), s2 = wave_red_sum(u2 * u2);
        if (lane == 0) { s_red[wid * 2] = s; s_red[wid * 2 + 1] = s2; }
        __syncthreads();
        float S = s_red[grp * 4 + 0] + s_red[grp * 4 + 2];
        float S2 = s_red[grp * 4 + 1] + s_red[grp * 4 + 3];
        float m = S * (1.f / 128.f), v = S2 * (1.f / 128.f) - m * m;
        float y = fmaxf((u2 - m) * rsqrtf(v + 1e-5f) * a.ng[n2 * 128 + jj] + a.nbe[n2 * 128 + jj], 0.f);
        float d = wave_red_sum(y * a.nw2[n2 * 128 + jj]);
        __syncthreads();
        if (lane == 0) s_red[wid] = d;
        __syncthreads();
        if (jj == 0) {
          float npost = s_red[grp * 2] + s_red[grp * 2 + 1] + a.nb2[n2];
          float prow[M_];
#pragma unroll
          for (int m2 = 0; m2 < M_ - 1; ++m2) prow[m2] = a.post[n2 * M_ + m2 + 1];
          prow[M_ - 1] = npost;
#pragma unroll
          for (int m2 = 0; m2 < M_; ++m2) a.post[n2 * M_ + m2] = prow[m2];
          a.post_last[n2] = npost;
        }
        __syncthreads();
      }
    }
    gridbar(cnt, gen);
  }

  // ---- tail: syncv (4 p per block; tick 9 => L = M, full rows) ----
  if (tid < 4) {
    int p = g * 4 + tid;
    int i = a.pairs[p * 2], jn = a.pairs[p * 2 + 1];
    float dc = a.decay[p];
    float num = 0.f, den = 0.f;
#pragma unroll
    for (int l = 0; l < M_; ++l) {
      float r = expf(-dc * (float)(M_ - 1 - l));
      num += a.post[i * M_ + l] * r * a.post[jn * M_ + l];
      den += r;
    }
    a.syncv[p] = num / (den + 1e-8f);
  }
  gridbar(cnt, gen);

  // ---- sc_part: blocks 0..127 (64 p-chunks x 2 j-halves) ----
  if (g < 128) {
    int j = (g & 1) * 256 + tid;
    int pb = g >> 1;
    if (tid < 16) s_sv[tid] = a.syncv[pb * 16 + tid];
    __syncthreads();
    float acc = 0.f;
#pragma unroll
    for (int i = 0; i < 16; ++i)
      acc += s_sv[i] * a.rdw1[(64 + pb * 16 + i) * 512 + j];
    a.sc_part[pb * 512 + j] = acc;
  }
  gridbar(cnt, gen);

  // ---- sc reduce: blocks 0,1 -> sc[512] (+bias) ----
  if (g < 2) {
    int j = g * 256 + tid;
    float v = a.rdb1[j];
#pragma unroll 8
    for (int r = 0; r < 64; ++r) v += a.sc_part[r * 512 + j];
    a.sc[j] = v;
  }
}

// Readout MLP, 4 batch rows/block (256 blocks x 512).
__global__ __launch_bounds__(512)
void k_read(const float* __restrict__ values_g, const float* __restrict__ sc,
            const float* __restrict__ rdw1,
            const float* __restrict__ rdg1, const float* __restrict__ rdbe1,
            const float* __restrict__ rdw2, const float* __restrict__ rdb2,
            const float* __restrict__ rdg2, const float* __restrict__ rdbe2,
            const float* __restrict__ rdw3, const float* __restrict__ rdb3,
            float* __restrict__ out) {
  int tid = threadIdx.x;
  int b0 = blockIdx.x * 4;
  __shared__ float vals[4][64];
  __shared__ float r1[4][512];
  __shared__ float r2[4][64];
  __shared__ float red[4][16];
  __shared__ float p2[8][4][64];
  for (int i = tid; i < 256; i += 512) {
    int r = i >> 6;
    vals[r][i & 63] = values_g[(b0 + r) * 64 + (i & 63)];
  }
  __syncthreads();
  float base = sc[tid];
  float u[4];
#pragma unroll
  for (int r = 0; r < 4; ++r) u[r] = base;
  for (int k = 0; k < 64; ++k) {
    float w = rdw1[k * 512 + tid];
#pragma unroll
    for (int r = 0; r < 4; ++r) u[r] += vals[r][k] * w;
  }
  int wid = tid >> 6, lane = tid & 63;
#pragma unroll
  for (int r = 0; r < 4; ++r) {
    float s = wave_red_sum(u[r]), s2 = wave_red_sum(u[r] * u[r]);
    if (lane == 0) { red[r][wid * 2] = s; red[r][wid * 2 + 1] = s2; }
  }
  __syncthreads();
  float gg = rdg1[tid], bb = rdbe1[tid];
#pragma unroll
  for (int r = 0; r < 4; ++r) {
    float S = 0.f, S2 = 0.f;
#pragma unroll
    for (int w = 0; w < 8; ++w) { S += red[r][w * 2]; S2 += red[r][w * 2 + 1]; }
    float m = S * (1.f / 512.f), v = S2 * (1.f / 512.f) - m * m;
    float y = (u[r] - m) * rsqrtf(v + 1e-5f) * gg + bb;
    r1[r][tid] = fmaxf(y, 0.f);
  }
  __syncthreads();
  int o = tid & 63, kq = tid >> 6;
  float u2[4] = {0.f, 0.f, 0.f, 0.f};
#pragma unroll
  for (int kk = 0; kk < 64; ++kk) {
    int k = kq * 64 + kk;
    float w = rdw2[k * 64 + o];
#pragma unroll
    for (int r = 0; r < 4; ++r) u2[r] += r1[r][k] * w;
  }
#pragma unroll
  for (int r = 0; r < 4; ++r) p2[kq][r][o] = u2[r];
  __syncthreads();
  if (tid < 256) {
    int r = tid >> 6, o2 = tid & 63;
    float v = rdb2[o2];
#pragma unroll
    for (int gq = 0; gq < 8; ++gq) v += p2[gq][r][o2];
    float s = wave_red_sum(v), s2 = wave_red_sum(v * v);
    float m = s * (1.f / 64.f), var = s2 * (1.f / 64.f) - m * m;
    float y = (v - m) * rsqrtf(var + 1e-5f) * rdg2[o2] + rdbe2[o2];
    r2[r][o2] = fmaxf(y, 0.f);
  }
  __syncthreads();
  if (tid < 40) {
    int r = tid / 10, o3 = tid - r * 10;
    float acc = rdb3[o3];
#pragma unroll
    for (int k = 0; k < 64; ++k) acc += r2[r][k] * rdw3[k * 10 + o3];
    out[(b0 + r) * 10 + o3] = acc;
  }
}

extern "C" void kernel_launch(void* const* d_in, const int* in_sizes, int n_in,
                              void* d_out, int out_size, void* d_ws, size_t ws_size,
                              hipStream_t stream) {
  const float* x     = (const float*)d_in[0];
  const float* post0 = (const float*)d_in[1];
  const float* pre0  = (const float*)d_in[2];
  const int*   pairs = (const int*)d_in[3];
  const float* decay = (const float*)d_in[4];
  const float* ie_w1 = (const float*)d_in[5];
  const float* ie_b1 = (const float*)d_in[6];
  const float* ie_g1 = (const float*)d_in[7];
  const float* ie_be1= (const float*)d_in[8];
  const float* ie_w2 = (const float*)d_in[9];
  const float* ie_b2 = (const float*)d_in[10];
  const float* ie_g2 = (const float*)d_in[11];
  const float* ie_be2= (const float*)d_in[12];
  const float* ie_w3 = (const float*)d_in[13];
  const float* ie_b3 = (const float*)d_in[14];
  const float* sy_w1 = (const float*)d_in[15];
  const float* sy_b1 = (const float*)d_in[16];
  const float* sy_g  = (const float*)d_in[17];
  const float* sy_be = (const float*)d_in[18];
  const float* sy_w2 = (const float*)d_in[19];
  const float* sy_b2 = (const float*)d_in[20];
  const float* nm_w1 = (const float*)d_in[21];
  const float* nm_b1 = (const float*)d_in[22];
  const float* nm_g  = (const float*)d_in[23];
  const float* nm_be = (const float*)d_in[24];
  const float* nm_w2 = (const float*)d_in[25];
  const float* nm_b2 = (const float*)d_in[26];
  const float* val_w = (const float*)d_in[29];
  const float* val_b = (const float*)d_in[30];
  const float* rd_w1 = (const float*)d_in[33];
  const float* rd_b1 = (const float*)d_in[34];
  const float* rd_g1 = (const float*)d_in[35];
  const float* rd_be1= (const float*)d_in[36];
  const float* rd_w2 = (const float*)d_in[37];
  const float* rd_b2 = (const float*)d_in[38];
  const float* rd_g2 = (const float*)d_in[39];
  const float* rd_be2= (const float*)d_in[40];
  const float* rd_w3 = (const float*)d_in[41];
  const float* rd_b3 = (const float*)d_in[42];
  float* out = (float*)d_out;

  float* ws = (float*)d_ws;
  float* post      = ws;                  // 40960
  float* pre       = ws + 40960;          // 40960
  float* post_last = ws + 81920;          // 4096
  float* enc       = ws + 86016;          // 4096
  float* values    = ws + 90112;          // 65536
  float* c_part    = ws + 155648;         // 64*256 = 16384
  float* hb_part   = ws + 172032;         // 128*256 = 32768
  float* syncv     = ws + 204800;         // 1024
  float* sc_part   = ws + 205824;         // 64*512 = 32768
  float* sc        = ws + 238592;         // 512
  unsigned* bar    = (unsigned*)(ws + 239104);  // cnt, gen

  k_init<<<NBLK, 256, 0, stream>>>(post0, pre0, post, pre, post_last, bar);
  k_enc<<<B_ / 2, 256, 0, stream>>>(x, ie_w1, ie_b1, ie_g1, ie_be1,
                                    ie_w2, ie_b2, ie_g2, ie_be2,
                                    ie_w3, ie_b3, val_w, val_b, enc, values);

  PersistArgs pa;
  pa.enc = enc; pa.syw1 = sy_w1; pa.syb1 = sy_b1; pa.syg = sy_g; pa.sybe = sy_be;
  pa.syw2 = sy_w2; pa.syb2 = sy_b2;
  pa.nw1 = nm_w1; pa.nb1 = nm_b1; pa.ng = nm_g; pa.nbe = nm_be; pa.nw2 = nm_w2; pa.nb2 = nm_b2;
  pa.pairs = pairs; pa.decay = decay;
  pa.rdw1 = rd_w1; pa.rdb1 = rd_b1;
  pa.post = post; pa.pre = pre; pa.post_last = post_last;
  pa.c_part = c_part; pa.hb_part = hb_part; pa.syncv = syncv;
  pa.sc_part = sc_part; pa.sc = sc;
  pa.bar = bar;
  k_persist<<<NBLK, 256, 0, stream>>>(pa);

  k_read<<<B_ / 4, 512, 0, stream>>>(values, sc, rd_w1, rd_g1, rd_be1,
                                     rd_w2, rd_b2, rd_g2, rd_be2, rd_w3, rd_b3, out);
}

// Round 5
// 485.957 us; speedup vs baseline: 5.6640x; 5.6640x over previous
//
#include <hip/hip_runtime.h>

#define N_ 4096
#define M_ 10
#define T_ 10
#define B_ 1024
#define P_ 1024
#define NBLK 256
#define NTHR 512

__device__ __forceinline__ float wave_red_sum(float v) {
#pragma unroll
  for (int m = 32; m >= 1; m >>= 1) v += __shfl_xor(v, m);
  return v;
}

// Agent-scope bypass accessors: served at the coherence point (MALL), never from
// the non-coherent per-XCD L2s -> no fences (buffer_inv/wbl2) needed anywhere.
__device__ __forceinline__ float gld(const float* p) {
  return __hip_atomic_load(p, __ATOMIC_RELAXED, __HIP_MEMORY_SCOPE_AGENT);
}
__device__ __forceinline__ void gst(float* p, float v) {
  __hip_atomic_store(p, v, __ATOMIC_RELAXED, __HIP_MEMORY_SCOPE_AGENT);
}

// Relaxed-only grid barrier. Ordering via in-order wave issue + explicit vmcnt
// drains; zero cache-maintenance ops (the round-4 killer was acquire's buffer_inv).
__device__ __forceinline__ void gridbar(unsigned* cnt, unsigned* gen) {
  asm volatile("s_waitcnt vmcnt(0)" ::: "memory");  // my bypass stores are at MALL
  __syncthreads();
  if (threadIdx.x == 0) {
    unsigned g = __hip_atomic_load(gen, __ATOMIC_RELAXED, __HIP_MEMORY_SCOPE_AGENT);
    unsigned a = __hip_atomic_fetch_add(cnt, 1u, __ATOMIC_RELAXED, __HIP_MEMORY_SCOPE_AGENT);
    if (a == (unsigned)(NBLK - 1)) {
      __hip_atomic_store(cnt, 0u, __ATOMIC_RELAXED, __HIP_MEMORY_SCOPE_AGENT);
      asm volatile("s_waitcnt vmcnt(0)" ::: "memory");  // cnt=0 durable before gen++
      __hip_atomic_store(gen, g + 1u, __ATOMIC_RELAXED, __HIP_MEMORY_SCOPE_AGENT);
    } else {
      unsigned cur;
      do {
        __builtin_amdgcn_s_sleep(2);
        cur = __hip_atomic_load(gen, __ATOMIC_RELAXED, __HIP_MEMORY_SCOPE_AGENT);
      } while (cur == g);
    }
  }
  asm volatile("" ::: "memory");
  __syncthreads();
}

// Zero barrier state each launch (replay-safe).
__global__ void k_init(unsigned* __restrict__ bar) {
  if (threadIdx.x < 2)
    __hip_atomic_store(bar + threadIdx.x, 0u, __ATOMIC_RELAXED, __HIP_MEMORY_SCOPE_AGENT);
}

// Fused encoder (verified passing in round 4): 512 blocks x 256 thr, 2 rows/block.
__global__ __launch_bounds__(256)
void k_enc(const float* __restrict__ x,
           const float* __restrict__ w1, const float* __restrict__ b1,
           const float* __restrict__ g1, const float* __restrict__ be1,
           const float* __restrict__ w2, const float* __restrict__ b2,
           const float* __restrict__ g2, const float* __restrict__ be2,
           const float* __restrict__ w3, const float* __restrict__ b3,
           const float* __restrict__ vw, const float* __restrict__ vb,
           float* __restrict__ enc_g, float* __restrict__ values_g) {
  const int tid = threadIdx.x;
  const int b0 = blockIdx.x * 2;
  const int kh = tid >> 7, j = tid & 127;
  __shared__ float fx[2][784];
  __shared__ float sp[2][2][128];
  __shared__ float e1[2][128];
  __shared__ float e2[2][32];
  __shared__ float encs[2][4];
  __shared__ float red[2][2][2];

  for (int i = tid; i < 2 * 784; i += 256) {
    int r = i / 784, k = i - r * 784;
    fx[r][k] = x[(b0 + r) * 784 + k];
  }
  __syncthreads();

  float a0 = 0.f, a1 = 0.f;
  const int kbeg = kh * 392;
#pragma unroll 4
  for (int k = kbeg; k < kbeg + 392; ++k) {
    float w = w1[k * 128 + j];
    a0 += fx[0][k] * w;
    a1 += fx[1][k] * w;
  }
  sp[kh][0][j] = a0;
  sp[kh][1][j] = a1;
  __syncthreads();

  float acc0 = 0.f, acc1 = 0.f;
  if (kh == 0) {
    float bb = b1[j];
    acc0 = sp[0][0][j] + sp[1][0][j] + bb;
    acc1 = sp[0][1][j] + sp[1][1][j] + bb;
    int wid = j >> 6;
    float s0 = wave_red_sum(acc0), q0 = wave_red_sum(acc0 * acc0);
    float s1 = wave_red_sum(acc1), q1 = wave_red_sum(acc1 * acc1);
    if ((j & 63) == 0) {
      red[wid][0][0] = s0; red[wid][0][1] = q0;
      red[wid][1][0] = s1; red[wid][1][1] = q1;
    }
  }
  __syncthreads();
  if (kh == 0) {
    float gg = g1[j], bbe = be1[j];
    float S0 = red[0][0][0] + red[1][0][0], Q0 = red[0][0][1] + red[1][0][1];
    float S1 = red[0][1][0] + red[1][1][0], Q1 = red[0][1][1] + red[1][1][1];
    float m0 = S0 * (1.f / 128.f), v0 = Q0 * (1.f / 128.f) - m0 * m0;
    float m1 = S1 * (1.f / 128.f), v1 = Q1 * (1.f / 128.f) - m1 * m1;
    e1[0][j] = fmaxf((acc0 - m0) * rsqrtf(v0 + 1e-5f) * gg + bbe, 0.f);
    e1[1][j] = fmaxf((acc1 - m1) * rsqrtf(v1 + 1e-5f) * gg + bbe, 0.f);
  }
  __syncthreads();

  if (tid < 64) {
    int r = tid >> 5, jj = tid & 31;
    float u = b2[jj];
    for (int k = 0; k < 128; ++k) u += e1[r][k] * w2[k * 32 + jj];
    float ss = u, ss2 = u * u;
#pragma unroll
    for (int m = 16; m >= 1; m >>= 1) { ss += __shfl_xor(ss, m, 32); ss2 += __shfl_xor(ss2, m, 32); }
    float mm = ss * (1.f / 32.f), vv = ss2 * (1.f / 32.f) - mm * mm;
    e2[r][jj] = fmaxf((u - mm) * rsqrtf(vv + 1e-5f) * g2[jj] + be2[jj], 0.f);
  }
  __syncthreads();

  if (tid < 8) {
    int r = tid >> 2, o = tid & 3;
    float u = b3[o];
    for (int k = 0; k < 32; ++k) u += e2[r][k] * w3[k * 4 + o];
    encs[r][o] = u;
    enc_g[(b0 + r) * 4 + o] = u;
  }
  __syncthreads();

  if (tid < 128) {  // values; softmax over size-1 axis == 1 -> att == values
    int r = tid >> 6, v = tid & 63;
    float u = vb[v];
#pragma unroll
    for (int o = 0; o < 4; ++o) u += encs[r][o] * vw[o * 64 + v];
    values_g[(b0 + r) * 64 + v] = u;
  }
}

struct PArgs {
  const float *post0, *pre0, *enc, *syw1, *syb1, *syg, *sybe, *syw2, *syb2;
  const float *nw1, *nb1, *ng, *nbe, *nw2, *nb2;
  const int* pairs;
  const float* decay;
  const float *rdw1, *rdb1;
  float *pc, *hb, *postG, *syncv, *scp, *sc;
  unsigned* bar;
};

// Persistent kernel: T=10 recurrence + sync + sc. 256 blocks x 512 threads.
// Each block owns n in [16g, 16g+16): post/pre rows live in LDS for the whole
// kernel. Weights read with NORMAL (cacheable) loads -> warm L2 across ticks.
// Only the small shared intermediates (pc, hb, postG, syncv, scp, sc) use
// bypass (agent-scope relaxed) accesses.
__global__ __launch_bounds__(NTHR)
void k_persist(PArgs a) {
  const int g = blockIdx.x, tid = threadIdx.x;
  const int j = tid & 255, half = tid >> 8;
  const int lane = tid & 63;
  const int n0 = g * 16;
  __shared__ float s_post[16][M_];
  __shared__ float s_pre[16][M_];
  __shared__ float s_hbar[256];
  __shared__ float s_tmp[2][256];
  __shared__ float s_part[32][16];
  __shared__ float s_red[16];
  __shared__ float s_pl[16];
  __shared__ float s_enc[32][4];
  unsigned* cnt = a.bar;
  unsigned* gen = a.bar + 1;

  // ---- prologue: own rows into LDS; pc row for tick 0 ----
  if (tid < 160) {
    int r = tid / 10, m = tid - r * 10;
    s_post[r][m] = a.post0[(n0 + r) * M_ + m];
    s_pre[r][m]  = a.pre0[(n0 + r) * M_ + m];
  }
  __syncthreads();
  if (tid < 16) s_pl[tid] = s_post[tid][M_ - 1];
  __syncthreads();
  {
    float acc = 0.f;
#pragma unroll
    for (int r = 0; r < 8; ++r) {
      int n = half * 8 + r;
      acc += s_pl[n] * a.syw1[(4 + n0 + n) * 256 + j];
    }
    s_tmp[half][j] = acc;
  }
  __syncthreads();
  if (tid < 256) gst(&a.pc[g * 256 + tid], s_tmp[0][tid] + s_tmp[1][tid]);
  gridbar(cnt, gen);

  for (int t = 0; t < T_; ++t) {
    // ---- P2: blocks 0..31, 32 batch rows each -> hb[g][256] ----
    if (g < 32) {
      int b0 = g * 32;
      float cacc = 0.f;
      for (int r = half * 128; r < half * 128 + 128; ++r)
        cacc += gld(&a.pc[r * 256 + j]);
      s_tmp[half][j] = cacc;
      if (tid < 128) s_enc[tid >> 2][tid & 3] = a.enc[(b0 + (tid >> 2)) * 4 + (tid & 3)];
      __syncthreads();
      float cval = s_tmp[0][j] + s_tmp[1][j] + a.syb1[j];
      float w4[4];
#pragma unroll
      for (int o = 0; o < 4; ++o) w4[o] = a.syw1[o * 256 + j];
      float gg = a.syg[j], bb = a.sybe[j];
      float hacc = 0.f;
      for (int rd = 0; rd < 16; ++rd) {
        int rloc = rd * 2 + half;
        float u = cval;
#pragma unroll
        for (int o = 0; o < 4; ++o) u += s_enc[rloc][o] * w4[o];
        float s = wave_red_sum(u), s2 = wave_red_sum(u * u);
        int wv = tid >> 6;
        if (lane == 0) { s_red[wv * 2] = s; s_red[wv * 2 + 1] = s2; }
        __syncthreads();
        float S  = s_red[half * 8 + 0] + s_red[half * 8 + 2] + s_red[half * 8 + 4] + s_red[half * 8 + 6];
        float S2 = s_red[half * 8 + 1] + s_red[half * 8 + 3] + s_red[half * 8 + 5] + s_red[half * 8 + 7];
        float mm = S * (1.f / 256.f), vv = S2 * (1.f / 256.f) - mm * mm;
        hacc += fmaxf((u - mm) * rsqrtf(vv + 1e-5f) * gg + bb, 0.f);
        __syncthreads();
      }
      s_tmp[half][j] = hacc;
      __syncthreads();
      if (tid < 256) gst(&a.hb[g * 256 + tid], s_tmp[0][tid] + s_tmp[1][tid]);
    }
    gridbar(cnt, gen);

    // ---- P3: all blocks, own 16 n ----
    // hbar = colmean of hb[32][256]
    {
      float acc = 0.f;
#pragma unroll
      for (int r = 0; r < 16; ++r)
        acc += gld(&a.hb[(half * 16 + r) * 256 + j]);
      s_tmp[half][j] = acc;
      __syncthreads();
      if (tid < 256) s_hbar[tid] = (s_tmp[0][tid] + s_tmp[1][tid]) * (1.f / 1024.f);
      __syncthreads();
    }
    // npre for own 16 n; shift pre rows
    {
      int nl = tid & 15, kq = tid >> 4;
      float u = 0.f;
#pragma unroll
      for (int kk = 0; kk < 8; ++kk) {
        int k = kq * 8 + kk;
        u += s_hbar[k] * a.syw2[k * N_ + n0 + nl];
      }
      s_part[kq][nl] = u;
      __syncthreads();
      if (tid < 16) {
        float v = a.syb2[n0 + tid];
#pragma unroll
        for (int q = 0; q < 32; ++q) v += s_part[q][tid];
#pragma unroll
        for (int m = 0; m < M_ - 1; ++m) s_pre[tid][m] = s_pre[tid][m + 1];
        s_pre[tid][M_ - 1] = v;
      }
      __syncthreads();
    }
    // nm: 4 rounds x 4 n concurrent; shift post rows
    {
      int grp = tid >> 7, jj = tid & 127;
      int wv = tid >> 6;
#pragma unroll
      for (int rd = 0; rd < 4; ++rd) {
        int nl = rd * 4 + grp;
        int n2 = n0 + nl;
        float u = a.nb1[n2 * 128 + jj];
#pragma unroll
        for (int m = 0; m < M_; ++m) u += s_pre[nl][m] * a.nw1[(n2 * M_ + m) * 128 + jj];
        float s = wave_red_sum(u), s2 = wave_red_sum(u * u);
        if (lane == 0) { s_red[wv * 2] = s; s_red[wv * 2 + 1] = s2; }
        __syncthreads();
        float S  = s_red[grp * 4 + 0] + s_red[grp * 4 + 2];
        float S2 = s_red[grp * 4 + 1] + s_red[grp * 4 + 3];
        float mm = S * (1.f / 128.f), vv = S2 * (1.f / 128.f) - mm * mm;
        float y = fmaxf((u - mm) * rsqrtf(vv + 1e-5f) * a.ng[n2 * 128 + jj] + a.nbe[n2 * 128 + jj], 0.f);
        float d = wave_red_sum(y * a.nw2[n2 * 128 + jj]);
        __syncthreads();
        if (lane == 0) s_red[wv] = d;
        __syncthreads();
        if (jj == 0) {
          float npost = s_red[grp * 2] + s_red[grp * 2 + 1] + a.nb2[n2];
#pragma unroll
          for (int m = 0; m < M_ - 1; ++m) s_post[nl][m] = s_post[nl][m + 1];
          s_post[nl][M_ - 1] = npost;
          s_pl[nl] = npost;
        }
        __syncthreads();
      }
    }
    // pc for next tick (last tick: flush post rows instead)
    if (t < T_ - 1) {
      float acc = 0.f;
#pragma unroll
      for (int r = 0; r < 8; ++r) {
        int n = half * 8 + r;
        acc += s_pl[n] * a.syw1[(4 + n0 + n) * 256 + j];
      }
      s_tmp[half][j] = acc;
      __syncthreads();
      if (tid < 256) gst(&a.pc[g * 256 + tid], s_tmp[0][tid] + s_tmp[1][tid]);
    } else {
      if (tid < 160) {
        int r = tid / 10, m = tid - r * 10;
        gst(&a.postG[(n0 + r) * M_ + m], s_post[r][m]);
      }
    }
    gridbar(cnt, gen);
  }

  // ---- syncv: 4 pairs per block (tick 9 => L = M, full rows) ----
  if (tid < 4) {
    int p = g * 4 + tid;
    int i = a.pairs[p * 2], jn = a.pairs[p * 2 + 1];
    float dc = a.decay[p];
    float num = 0.f, den = 0.f;
#pragma unroll
    for (int l = 0; l < M_; ++l) {
      float r = expf(-dc * (float)(M_ - 1 - l));
      num += gld(&a.postG[i * M_ + l]) * r * gld(&a.postG[jn * M_ + l]);
      den += r;
    }
    gst(&a.syncv[p], num / (den + 1e-8f));
  }
  gridbar(cnt, gen);

  // ---- sc partials: blocks 0..63, 16-p chunk x 512 j ----
  if (g < 64) {
    if (tid < 16) s_pl[tid] = gld(&a.syncv[g * 16 + tid]);
    __syncthreads();
    float acc = 0.f;
#pragma unroll
    for (int i2 = 0; i2 < 16; ++i2)
      acc += s_pl[i2] * a.rdw1[(64 + g * 16 + i2) * 512 + tid];
    gst(&a.scp[g * 512 + tid], acc);
  }
  gridbar(cnt, gen);

  // ---- sc reduce: block 0 ----
  if (g == 0) {
    float v = a.rdb1[tid];
    for (int r = 0; r < 64; ++r) v += gld(&a.scp[r * 512 + tid]);
    gst(&a.sc[tid], v);
  }
}

// Readout MLP, 4 batch rows/block (256 blocks x 512). (verified passing)
__global__ __launch_bounds__(512)
void k_read(const float* __restrict__ values_g, const float* __restrict__ sc,
            const float* __restrict__ rdw1,
            const float* __restrict__ rdg1, const float* __restrict__ rdbe1,
            const float* __restrict__ rdw2, const float* __restrict__ rdb2,
            const float* __restrict__ rdg2, const float* __restrict__ rdbe2,
            const float* __restrict__ rdw3, const float* __restrict__ rdb3,
            float* __restrict__ out) {
  int tid = threadIdx.x;
  int b0 = blockIdx.x * 4;
  __shared__ float vals[4][64];
  __shared__ float r1[4][512];
  __shared__ float r2[4][64];
  __shared__ float red[4][16];
  __shared__ float p2[8][4][64];
  for (int i = tid; i < 256; i += 512) {
    int r = i >> 6;
    vals[r][i & 63] = values_g[(b0 + r) * 64 + (i & 63)];
  }
  __syncthreads();
  float base = sc[tid];
  float u[4];
#pragma unroll
  for (int r = 0; r < 4; ++r) u[r] = base;
  for (int k = 0; k < 64; ++k) {
    float w = rdw1[k * 512 + tid];
#pragma unroll
    for (int r = 0; r < 4; ++r) u[r] += vals[r][k] * w;
  }
  int wid = tid >> 6, lane = tid & 63;
#pragma unroll
  for (int r = 0; r < 4; ++r) {
    float s = wave_red_sum(u[r]), s2 = wave_red_sum(u[r] * u[r]);
    if (lane == 0) { red[r][wid * 2] = s; red[r][wid * 2 + 1] = s2; }
  }
  __syncthreads();
  float gg = rdg1[tid], bb = rdbe1[tid];
#pragma unroll
  for (int r = 0; r < 4; ++r) {
    float S = 0.f, S2 = 0.f;
#pragma unroll
    for (int w = 0; w < 8; ++w) { S += red[r][w * 2]; S2 += red[r][w * 2 + 1]; }
    float m = S * (1.f / 512.f), v = S2 * (1.f / 512.f) - m * m;
    float y = (u[r] - m) * rsqrtf(v + 1e-5f) * gg + bb;
    r1[r][tid] = fmaxf(y, 0.f);
  }
  __syncthreads();
  int o = tid & 63, kq = tid >> 6;
  float u2[4] = {0.f, 0.f, 0.f, 0.f};
#pragma unroll
  for (int kk = 0; kk < 64; ++kk) {
    int k = kq * 64 + kk;
    float w = rdw2[k * 64 + o];
#pragma unroll
    for (int r = 0; r < 4; ++r) u2[r] += r1[r][k] * w;
  }
#pragma unroll
  for (int r = 0; r < 4; ++r) p2[kq][r][o] = u2[r];
  __syncthreads();
  if (tid < 256) {
    int r = tid >> 6, o2 = tid & 63;
    float v = rdb2[o2];
#pragma unroll
    for (int gq = 0; gq < 8; ++gq) v += p2[gq][r][o2];
    float s = wave_red_sum(v), s2 = wave_red_sum(v * v);
    float m = s * (1.f / 64.f), var = s2 * (1.f / 64.f) - m * m;
    float y = (v - m) * rsqrtf(var + 1e-5f) * rdg2[o2] + rdbe2[o2];
    r2[r][o2] = fmaxf(y, 0.f);
  }
  __syncthreads();
  if (tid < 40) {
    int r = tid / 10, o3 = tid - r * 10;
    float acc = rdb3[o3];
#pragma unroll
    for (int k = 0; k < 64; ++k) acc += r2[r][k] * rdw3[k * 10 + o3];
    out[(b0 + r) * 10 + o3] = acc;
  }
}

extern "C" void kernel_launch(void* const* d_in, const int* in_sizes, int n_in,
                              void* d_out, int out_size, void* d_ws, size_t ws_size,
                              hipStream_t stream) {
  const float* x     = (const float*)d_in[0];
  const float* post0 = (const float*)d_in[1];
  const float* pre0  = (const float*)d_in[2];
  const int*   pairs = (const int*)d_in[3];
  const float* decay = (const float*)d_in[4];
  const float* ie_w1 = (const float*)d_in[5];
  const float* ie_b1 = (const float*)d_in[6];
  const float* ie_g1 = (const float*)d_in[7];
  const float* ie_be1= (const float*)d_in[8];
  const float* ie_w2 = (const float*)d_in[9];
  const float* ie_b2 = (const float*)d_in[10];
  const float* ie_g2 = (const float*)d_in[11];
  const float* ie_be2= (const float*)d_in[12];
  const float* ie_w3 = (const float*)d_in[13];
  const float* ie_b3 = (const float*)d_in[14];
  const float* sy_w1 = (const float*)d_in[15];
  const float* sy_b1 = (const float*)d_in[16];
  const float* sy_g  = (const float*)d_in[17];
  const float* sy_be = (const float*)d_in[18];
  const float* sy_w2 = (const float*)d_in[19];
  const float* sy_b2 = (const float*)d_in[20];
  const float* nm_w1 = (const float*)d_in[21];
  const float* nm_b1 = (const float*)d_in[22];
  const float* nm_g  = (const float*)d_in[23];
  const float* nm_be = (const float*)d_in[24];
  const float* nm_w2 = (const float*)d_in[25];
  const float* nm_b2 = (const float*)d_in[26];
  const float* val_w = (const float*)d_in[29];
  const float* val_b = (const float*)d_in[30];
  const float* rd_w1 = (const float*)d_in[33];
  const float* rd_b1 = (const float*)d_in[34];
  const float* rd_g1 = (const float*)d_in[35];
  const float* rd_be1= (const float*)d_in[36];
  const float* rd_w2 = (const float*)d_in[37];
  const float* rd_b2 = (const float*)d_in[38];
  const float* rd_g2 = (const float*)d_in[39];
  const float* rd_be2= (const float*)d_in[40];
  const float* rd_w3 = (const float*)d_in[41];
  const float* rd_b3 = (const float*)d_in[42];
  float* out = (float*)d_out;

  float* ws = (float*)d_ws;
  float* postG  = ws;                   // 40960
  float* pc     = ws + 40960;           // 256*256 = 65536
  float* hb     = ws + 106496;          // 32*256  = 8192
  float* enc    = ws + 114688;          // 4096
  float* values = ws + 118784;          // 65536
  float* syncv  = ws + 184320;          // 1024
  float* scp    = ws + 185344;          // 64*512 = 32768
  float* sc     = ws + 218112;          // 512
  unsigned* bar = (unsigned*)(ws + 218624);  // cnt, gen

  k_init<<<1, 64, 0, stream>>>(bar);
  k_enc<<<B_ / 2, 256, 0, stream>>>(x, ie_w1, ie_b1, ie_g1, ie_be1,
                                    ie_w2, ie_b2, ie_g2, ie_be2,
                                    ie_w3, ie_b3, val_w, val_b, enc, values);

  PArgs pa;
  pa.post0 = post0; pa.pre0 = pre0; pa.enc = enc;
  pa.syw1 = sy_w1; pa.syb1 = sy_b1; pa.syg = sy_g; pa.sybe = sy_be;
  pa.syw2 = sy_w2; pa.syb2 = sy_b2;
  pa.nw1 = nm_w1; pa.nb1 = nm_b1; pa.ng = nm_g; pa.nbe = nm_be;
  pa.nw2 = nm_w2; pa.nb2 = nm_b2;
  pa.pairs = pairs; pa.decay = decay;
  pa.rdw1 = rd_w1; pa.rdb1 = rd_b1;
  pa.pc = pc; pa.hb = hb; pa.postG = postG; pa.syncv = syncv;
  pa.scp = scp; pa.sc = sc; pa.bar = bar;
  k_persist<<<NBLK, NTHR, 0, stream>>>(pa);

  k_read<<<B_ / 4, 512, 0, stream>>>(values, sc, rd_w1, rd_g1, rd_be1,
                                     rd_w2, rd_b2, rd_g2, rd_be2, rd_w3, rd_b3, out);
}

// Round 6
// 264.602 us; speedup vs baseline: 10.4022x; 1.8366x over previous
//
#include <hip/hip_runtime.h>

#define N_ 4096
#define M_ 10
#define T_ 10
#define B_ 1024
#define P_ 1024
#define NBLK 256
#define NTHR 512

__device__ __forceinline__ float wave_red_sum(float v) {
#pragma unroll
  for (int m = 32; m >= 1; m >>= 1) v += __shfl_xor(v, m);
  return v;
}

// Agent-scope bypass accessors: served at the coherence point, never stale in a
// non-coherent per-XCD L2 -> no cache-maintenance ops needed anywhere.
__device__ __forceinline__ float gld(const float* p) {
  return __hip_atomic_load(p, __ATOMIC_RELAXED, __HIP_MEMORY_SCOPE_AGENT);
}
__device__ __forceinline__ void gst(float* p, float v) {
  __hip_atomic_store(p, v, __ATOMIC_RELAXED, __HIP_MEMORY_SCOPE_AGENT);
}

// Monotonic hierarchical grid barrier (relaxed-only; no resets, no buffer_inv).
// Arrival: atomic add on cnts[g&7] (8 separate cachelines, stride 32 uints).
// Block 0 polls all 8 until they reach bar_no*32, then publishes gen = bar_no.
__device__ __forceinline__ void gridbar(unsigned* cnts, unsigned* gen,
                                        unsigned bar_no, int g) {
  asm volatile("s_waitcnt vmcnt(0)" ::: "memory");  // my bypass stores are durable
  __syncthreads();
  if (threadIdx.x == 0) {
    __hip_atomic_fetch_add(&cnts[(g & 7) * 32], 1u, __ATOMIC_RELAXED,
                           __HIP_MEMORY_SCOPE_AGENT);
    if (g == 0) {
      const unsigned target = bar_no * (NBLK / 8);
      bool done;
      do {
        done = true;
#pragma unroll
        for (int i = 0; i < 8; ++i)
          done &= (__hip_atomic_load(&cnts[i * 32], __ATOMIC_RELAXED,
                                     __HIP_MEMORY_SCOPE_AGENT) >= target);
        if (!done) __builtin_amdgcn_s_sleep(1);
      } while (!done);
      __hip_atomic_store(gen, bar_no, __ATOMIC_RELAXED, __HIP_MEMORY_SCOPE_AGENT);
    } else {
      while (__hip_atomic_load(gen, __ATOMIC_RELAXED, __HIP_MEMORY_SCOPE_AGENT) < bar_no)
        __builtin_amdgcn_s_sleep(1);
    }
  }
  asm volatile("" ::: "memory");
  __syncthreads();
}

// Zero barrier state each launch (replay-safe).
__global__ void k_init(unsigned* __restrict__ bar) {
  if (threadIdx.x < 512)
    __hip_atomic_store(bar + threadIdx.x, 0u, __ATOMIC_RELAXED, __HIP_MEMORY_SCOPE_AGENT);
}

// Fused encoder (verified): 512 blocks x 256 thr, 2 rows/block.
__global__ __launch_bounds__(256)
void k_enc(const float* __restrict__ x,
           const float* __restrict__ w1, const float* __restrict__ b1,
           const float* __restrict__ g1, const float* __restrict__ be1,
           const float* __restrict__ w2, const float* __restrict__ b2,
           const float* __restrict__ g2, const float* __restrict__ be2,
           const float* __restrict__ w3, const float* __restrict__ b3,
           const float* __restrict__ vw, const float* __restrict__ vb,
           float* __restrict__ enc_g, float* __restrict__ values_g) {
  const int tid = threadIdx.x;
  const int b0 = blockIdx.x * 2;
  const int kh = tid >> 7, j = tid & 127;
  __shared__ float fx[2][784];
  __shared__ float sp[2][2][128];
  __shared__ float e1[2][128];
  __shared__ float e2[2][32];
  __shared__ float encs[2][4];
  __shared__ float red[2][2][2];

  for (int i = tid; i < 2 * 784; i += 256) {
    int r = i / 784, k = i - r * 784;
    fx[r][k] = x[(b0 + r) * 784 + k];
  }
  __syncthreads();

  float a0 = 0.f, a1 = 0.f;
  const int kbeg = kh * 392;
#pragma unroll 4
  for (int k = kbeg; k < kbeg + 392; ++k) {
    float w = w1[k * 128 + j];
    a0 += fx[0][k] * w;
    a1 += fx[1][k] * w;
  }
  sp[kh][0][j] = a0;
  sp[kh][1][j] = a1;
  __syncthreads();

  float acc0 = 0.f, acc1 = 0.f;
  if (kh == 0) {
    float bb = b1[j];
    acc0 = sp[0][0][j] + sp[1][0][j] + bb;
    acc1 = sp[0][1][j] + sp[1][1][j] + bb;
    int wid = j >> 6;
    float s0 = wave_red_sum(acc0), q0 = wave_red_sum(acc0 * acc0);
    float s1 = wave_red_sum(acc1), q1 = wave_red_sum(acc1 * acc1);
    if ((j & 63) == 0) {
      red[wid][0][0] = s0; red[wid][0][1] = q0;
      red[wid][1][0] = s1; red[wid][1][1] = q1;
    }
  }
  __syncthreads();
  if (kh == 0) {
    float gg = g1[j], bbe = be1[j];
    float S0 = red[0][0][0] + red[1][0][0], Q0 = red[0][0][1] + red[1][0][1];
    float S1 = red[0][1][0] + red[1][1][0], Q1 = red[0][1][1] + red[1][1][1];
    float m0 = S0 * (1.f / 128.f), v0 = Q0 * (1.f / 128.f) - m0 * m0;
    float m1 = S1 * (1.f / 128.f), v1 = Q1 * (1.f / 128.f) - m1 * m1;
    e1[0][j] = fmaxf((acc0 - m0) * rsqrtf(v0 + 1e-5f) * gg + bbe, 0.f);
    e1[1][j] = fmaxf((acc1 - m1) * rsqrtf(v1 + 1e-5f) * gg + bbe, 0.f);
  }
  __syncthreads();

  if (tid < 64) {
    int r = tid >> 5, jj = tid & 31;
    float u = b2[jj];
    for (int k = 0; k < 128; ++k) u += e1[r][k] * w2[k * 32 + jj];
    float ss = u, ss2 = u * u;
#pragma unroll
    for (int m = 16; m >= 1; m >>= 1) { ss += __shfl_xor(ss, m, 32); ss2 += __shfl_xor(ss2, m, 32); }
    float mm = ss * (1.f / 32.f), vv = ss2 * (1.f / 32.f) - mm * mm;
    e2[r][jj] = fmaxf((u - mm) * rsqrtf(vv + 1e-5f) * g2[jj] + be2[jj], 0.f);
  }
  __syncthreads();

  if (tid < 8) {
    int r = tid >> 2, o = tid & 3;
    float u = b3[o];
    for (int k = 0; k < 32; ++k) u += e2[r][k] * w3[k * 4 + o];
    encs[r][o] = u;
    enc_g[(b0 + r) * 4 + o] = u;
  }
  __syncthreads();

  if (tid < 128) {  // values; softmax over size-1 axis == 1 -> att == values
    int r = tid >> 6, v = tid & 63;
    float u = vb[v];
#pragma unroll
    for (int o = 0; o < 4; ++o) u += encs[r][o] * vw[o * 64 + v];
    values_g[(b0 + r) * 64 + v] = u;
  }
}

struct PArgs {
  const float *post0, *pre0, *enc, *syw1, *syb1, *syg, *sybe, *syw2, *syb2;
  const float *nw1, *nb1, *ng, *nbe, *nw2, *nb2;
  const int* pairs;
  const float* decay;
  const float *rdw1, *rdb1;
  float *pc, *hb, *postG, *syncv, *scp, *sc;
  unsigned* bar;
};

// Persistent kernel, 256 blocks x 512 threads, 1 block/CU (LDS-limited).
// Each block owns n in [16g, 16g+16). nm_w1 slice (80 KB) + sy_w1 rows (16 KB)
// PINNED in LDS for all 10 ticks -> weight HBM traffic happens once, not 10x.
// Cross-block data (pc, hb, postG, syncv, scp, sc) via agent-scope bypass.
__global__ __launch_bounds__(NTHR)
void k_persist(PArgs a) {
  const int g = blockIdx.x, tid = threadIdx.x;
  const int j = tid & 255, half = tid >> 8;
  const int lane = tid & 63;
  const int n0 = g * 16;
  __shared__ float s_w1[16][M_][128];   // 80 KB: nm_w1 slice
  __shared__ float s_syw1[16][256];     // 16 KB: sy_w1 rows 4+n0..
  __shared__ float s_post[16][M_];
  __shared__ float s_pre[16][M_];
  __shared__ float s_pl[16];
  __shared__ float s_hbar[256];
  __shared__ float s_tmp[2][256];
  __shared__ float s_part[32][16];
  __shared__ float s_red[16];
  __shared__ float s_enc[16][4];
  unsigned* cnts = a.bar;        // [0..255] stride-32 counters
  unsigned* gen  = a.bar + 256;
  unsigned bar_no = 0;

  // ---- prologue: pin weights, load state, first pc ----
  {
    float* w1f = &s_w1[0][0][0];
    const float* src = a.nw1 + n0 * M_ * 128;
    for (int i = tid; i < 16 * M_ * 128; i += NTHR) w1f[i] = src[i];
    float* syf = &s_syw1[0][0];
    const float* ssrc = a.syw1 + (4 + n0) * 256;
    for (int i = tid; i < 16 * 256; i += NTHR) syf[i] = ssrc[i];
    if (tid < 160) {
      int r = tid / 10, m = tid - r * 10;
      s_post[r][m] = a.post0[(n0 + r) * M_ + m];
      s_pre[r][m]  = a.pre0[(n0 + r) * M_ + m];
    }
  }
  __syncthreads();
  if (tid < 16) s_pl[tid] = s_post[tid][M_ - 1];
  __syncthreads();
  {
    float acc = 0.f;
#pragma unroll
    for (int r = 0; r < 8; ++r) {
      int n = half * 8 + r;
      acc += s_pl[n] * s_syw1[n][j];
    }
    s_tmp[half][j] = acc;
  }
  __syncthreads();
  if (tid < 256) gst(&a.pc[g * 256 + tid], s_tmp[0][tid] + s_tmp[1][tid]);
  ++bar_no; gridbar(cnts, gen, bar_no, g);

  for (int t = 0; t < T_; ++t) {
    // ---- P2: blocks 0..63, 16 batch rows each -> hb[g][256] ----
    if (g < 64) {
      int b0 = g * 16;
      float cacc = 0.f;
#pragma unroll 8
      for (int r = half * 128; r < half * 128 + 128; ++r)
        cacc += gld(&a.pc[r * 256 + j]);
      s_tmp[half][j] = cacc;
      if (tid < 64) s_enc[tid >> 2][tid & 3] = a.enc[(b0 + (tid >> 2)) * 4 + (tid & 3)];
      __syncthreads();
      float cval = s_tmp[0][j] + s_tmp[1][j] + a.syb1[j];
      float w4[4];
#pragma unroll
      for (int o = 0; o < 4; ++o) w4[o] = a.syw1[o * 256 + j];
      float gg = a.syg[j], bb = a.sybe[j];
      float hacc = 0.f;
      __syncthreads();
      for (int rd = 0; rd < 8; ++rd) {
        int rloc = rd * 2 + half;
        float u = cval;
#pragma unroll
        for (int o = 0; o < 4; ++o) u += s_enc[rloc][o] * w4[o];
        float s = wave_red_sum(u), s2 = wave_red_sum(u * u);
        int wv = tid >> 6;
        if (lane == 0) { s_red[wv * 2] = s; s_red[wv * 2 + 1] = s2; }
        __syncthreads();
        float S  = s_red[half * 8 + 0] + s_red[half * 8 + 2] + s_red[half * 8 + 4] + s_red[half * 8 + 6];
        float S2 = s_red[half * 8 + 1] + s_red[half * 8 + 3] + s_red[half * 8 + 5] + s_red[half * 8 + 7];
        float mm = S * (1.f / 256.f), vv = S2 * (1.f / 256.f) - mm * mm;
        hacc += fmaxf((u - mm) * rsqrtf(vv + 1e-5f) * gg + bb, 0.f);
        __syncthreads();
      }
      s_tmp[half][j] = hacc;
      __syncthreads();
      if (tid < 256) gst(&a.hb[g * 256 + tid], s_tmp[0][tid] + s_tmp[1][tid]);
    }
    ++bar_no; gridbar(cnts, gen, bar_no, g);

    // ---- P3: all blocks, own 16 n ----
    {
      float acc = 0.f;
#pragma unroll 8
      for (int r = half * 32; r < half * 32 + 32; ++r)
        acc += gld(&a.hb[r * 256 + j]);
      s_tmp[half][j] = acc;
      __syncthreads();
      if (tid < 256) s_hbar[tid] = (s_tmp[0][tid] + s_tmp[1][tid]) * (1.f / 1024.f);
      __syncthreads();
    }
    {  // npre + pre shift
      int nl = tid & 15, kq = tid >> 4;
      float u = 0.f;
#pragma unroll
      for (int kk = 0; kk < 8; ++kk) {
        int k = kq * 8 + kk;
        u += s_hbar[k] * a.syw2[k * N_ + n0 + nl];
      }
      s_part[kq][nl] = u;
      __syncthreads();
      if (tid < 16) {
        float v = a.syb2[n0 + tid];
#pragma unroll
        for (int q = 0; q < 32; ++q) v += s_part[q][tid];
#pragma unroll
        for (int m = 0; m < M_ - 1; ++m) s_pre[tid][m] = s_pre[tid][m + 1];
        s_pre[tid][M_ - 1] = v;
      }
      __syncthreads();
    }
    {  // nm: 4 rounds x 4 n concurrent; post shift
      int grp = tid >> 7, jj = tid & 127;
      int wv = tid >> 6;
#pragma unroll
      for (int rd = 0; rd < 4; ++rd) {
        int nl = rd * 4 + grp;
        int n2 = n0 + nl;
        float u = a.nb1[n2 * 128 + jj];
#pragma unroll
        for (int m = 0; m < M_; ++m) u += s_pre[nl][m] * s_w1[nl][m][jj];
        float s = wave_red_sum(u), s2 = wave_red_sum(u * u);
        if (lane == 0) { s_red[wv * 2] = s; s_red[wv * 2 + 1] = s2; }
        __syncthreads();
        float S  = s_red[grp * 4 + 0] + s_red[grp * 4 + 2];
        float S2 = s_red[grp * 4 + 1] + s_red[grp * 4 + 3];
        float mm = S * (1.f / 128.f), vv = S2 * (1.f / 128.f) - mm * mm;
        float y = fmaxf((u - mm) * rsqrtf(vv + 1e-5f) * a.ng[n2 * 128 + jj] + a.nbe[n2 * 128 + jj], 0.f);
        float d = wave_red_sum(y * a.nw2[n2 * 128 + jj]);
        __syncthreads();
        if (lane == 0) s_red[wv] = d;
        __syncthreads();
        if (jj == 0) {
          float npost = s_red[grp * 2] + s_red[grp * 2 + 1] + a.nb2[n2];
#pragma unroll
          for (int m = 0; m < M_ - 1; ++m) s_post[nl][m] = s_post[nl][m + 1];
          s_post[nl][M_ - 1] = npost;
          s_pl[nl] = npost;
        }
        __syncthreads();
      }
    }
    // pc for next tick; last tick flushes post rows instead
    if (t < T_ - 1) {
      float acc = 0.f;
#pragma unroll
      for (int r = 0; r < 8; ++r) {
        int n = half * 8 + r;
        acc += s_pl[n] * s_syw1[n][j];
      }
      s_tmp[half][j] = acc;
      __syncthreads();
      if (tid < 256) gst(&a.pc[g * 256 + tid], s_tmp[0][tid] + s_tmp[1][tid]);
    } else {
      if (tid < 160) {
        int r = tid / 10, m = tid - r * 10;
        gst(&a.postG[(n0 + r) * M_ + m], s_post[r][m]);
      }
    }
    ++bar_no; gridbar(cnts, gen, bar_no, g);
  }

  // ---- syncv: 4 pairs per block (tick 9 => L = M, full rows) ----
  if (tid < 4) {
    int p = g * 4 + tid;
    int i = a.pairs[p * 2], jn = a.pairs[p * 2 + 1];
    float dc = a.decay[p];
    float num = 0.f, den = 0.f;
#pragma unroll
    for (int l = 0; l < M_; ++l) {
      float r = expf(-dc * (float)(M_ - 1 - l));
      num += gld(&a.postG[i * M_ + l]) * r * gld(&a.postG[jn * M_ + l]);
      den += r;
    }
    gst(&a.syncv[p], num / (den + 1e-8f));
  }
  ++bar_no; gridbar(cnts, gen, bar_no, g);

  // ---- sc partials: blocks 0..63, 16-p chunk x 512 j ----
  if (g < 64) {
    if (tid < 16) s_pl[tid] = gld(&a.syncv[g * 16 + tid]);
    __syncthreads();
    float acc = 0.f;
#pragma unroll
    for (int i2 = 0; i2 < 16; ++i2)
      acc += s_pl[i2] * a.rdw1[(64 + g * 16 + i2) * 512 + tid];
    gst(&a.scp[g * 512 + tid], acc);
  }
  ++bar_no; gridbar(cnts, gen, bar_no, g);

  // ---- sc reduce: block 0 ----
  if (g == 0) {
    float v = a.rdb1[tid];
#pragma unroll 8
    for (int r = 0; r < 64; ++r) v += gld(&a.scp[r * 512 + tid]);
    gst(&a.sc[tid], v);
  }
}

// Readout MLP, 4 batch rows/block (256 blocks x 512). (verified)
__global__ __launch_bounds__(512)
void k_read(const float* __restrict__ values_g, const float* __restrict__ sc,
            const float* __restrict__ rdw1,
            const float* __restrict__ rdg1, const float* __restrict__ rdbe1,
            const float* __restrict__ rdw2, const float* __restrict__ rdb2,
            const float* __restrict__ rdg2, const float* __restrict__ rdbe2,
            const float* __restrict__ rdw3, const float* __restrict__ rdb3,
            float* __restrict__ out) {
  int tid = threadIdx.x;
  int b0 = blockIdx.x * 4;
  __shared__ float vals[4][64];
  __shared__ float r1[4][512];
  __shared__ float r2[4][64];
  __shared__ float red[4][16];
  __shared__ float p2[8][4][64];
  for (int i = tid; i < 256; i += 512) {
    int r = i >> 6;
    vals[r][i & 63] = values_g[(b0 + r) * 64 + (i & 63)];
  }
  __syncthreads();
  float base = sc[tid];
  float u[4];
#pragma unroll
  for (int r = 0; r < 4; ++r) u[r] = base;
  for (int k = 0; k < 64; ++k) {
    float w = rdw1[k * 512 + tid];
#pragma unroll
    for (int r = 0; r < 4; ++r) u[r] += vals[r][k] * w;
  }
  int wid = tid >> 6, lane = tid & 63;
#pragma unroll
  for (int r = 0; r < 4; ++r) {
    float s = wave_red_sum(u[r]), s2 = wave_red_sum(u[r] * u[r]);
    if (lane == 0) { red[r][wid * 2] = s; red[r][wid * 2 + 1] = s2; }
  }
  __syncthreads();
  float gg = rdg1[tid], bb = rdbe1[tid];
#pragma unroll
  for (int r = 0; r < 4; ++r) {
    float S = 0.f, S2 = 0.f;
#pragma unroll
    for (int w = 0; w < 8; ++w) { S += red[r][w * 2]; S2 += red[r][w * 2 + 1]; }
    float m = S * (1.f / 512.f), v = S2 * (1.f / 512.f) - m * m;
    float y = (u[r] - m) * rsqrtf(v + 1e-5f) * gg + bb;
    r1[r][tid] = fmaxf(y, 0.f);
  }
  __syncthreads();
  int o = tid & 63, kq = tid >> 6;
  float u2[4] = {0.f, 0.f, 0.f, 0.f};
#pragma unroll
  for (int kk = 0; kk < 64; ++kk) {
    int k = kq * 64 + kk;
    float w = rdw2[k * 64 + o];
#pragma unroll
    for (int r = 0; r < 4; ++r) u2[r] += r1[r][k] * w;
  }
#pragma unroll
  for (int r = 0; r < 4; ++r) p2[kq][r][o] = u2[r];
  __syncthreads();
  if (tid < 256) {
    int r = tid >> 6, o2 = tid & 63;
    float v = rdb2[o2];
#pragma unroll
    for (int gq = 0; gq < 8; ++gq) v += p2[gq][r][o2];
    float s = wave_red_sum(v), s2 = wave_red_sum(v * v);
    float m = s * (1.f / 64.f), var = s2 * (1.f / 64.f) - m * m;
    float y = (v - m) * rsqrtf(var + 1e-5f) * rdg2[o2] + rdbe2[o2];
    r2[r][o2] = fmaxf(y, 0.f);
  }
  __syncthreads();
  if (tid < 40) {
    int r = tid / 10, o3 = tid - r * 10;
    float acc = rdb3[o3];
#pragma unroll
    for (int k = 0; k < 64; ++k) acc += r2[r][k] * rdw3[k * 10 + o3];
    out[(b0 + r) * 10 + o3] = acc;
  }
}

extern "C" void kernel_launch(void* const* d_in, const int* in_sizes, int n_in,
                              void* d_out, int out_size, void* d_ws, size_t ws_size,
                              hipStream_t stream) {
  const float* x     = (const float*)d_in[0];
  const float* post0 = (const float*)d_in[1];
  const float* pre0  = (const float*)d_in[2];
  const int*   pairs = (const int*)d_in[3];
  const float* decay = (const float*)d_in[4];
  const float* ie_w1 = (const float*)d_in[5];
  const float* ie_b1 = (const float*)d_in[6];
  const float* ie_g1 = (const float*)d_in[7];
  const float* ie_be1= (const float*)d_in[8];
  const float* ie_w2 = (const float*)d_in[9];
  const float* ie_b2 = (const float*)d_in[10];
  const float* ie_g2 = (const float*)d_in[11];
  const float* ie_be2= (const float*)d_in[12];
  const float* ie_w3 = (const float*)d_in[13];
  const float* ie_b3 = (const float*)d_in[14];
  const float* sy_w1 = (const float*)d_in[15];
  const float* sy_b1 = (const float*)d_in[16];
  const float* sy_g  = (const float*)d_in[17];
  const float* sy_be = (const float*)d_in[18];
  const float* sy_w2 = (const float*)d_in[19];
  const float* sy_b2 = (const float*)d_in[20];
  const float* nm_w1 = (const float*)d_in[21];
  const float* nm_b1 = (const float*)d_in[22];
  const float* nm_g  = (const float*)d_in[23];
  const float* nm_be = (const float*)d_in[24];
  const float* nm_w2 = (const float*)d_in[25];
  const float* nm_b2 = (const float*)d_in[26];
  const float* val_w = (const float*)d_in[29];
  const float* val_b = (const float*)d_in[30];
  const float* rd_w1 = (const float*)d_in[33];
  const float* rd_b1 = (const float*)d_in[34];
  const float* rd_g1 = (const float*)d_in[35];
  const float* rd_be1= (const float*)d_in[36];
  const float* rd_w2 = (const float*)d_in[37];
  const float* rd_b2 = (const float*)d_in[38];
  const float* rd_g2 = (const float*)d_in[39];
  const float* rd_be2= (const float*)d_in[40];
  const float* rd_w3 = (const float*)d_in[41];
  const float* rd_b3 = (const float*)d_in[42];
  float* out = (float*)d_out;

  float* ws = (float*)d_ws;
  float* postG  = ws;                   // 40960
  float* pc     = ws + 40960;           // 256*256 = 65536
  float* hb     = ws + 106496;          // 64*256  = 16384
  float* enc    = ws + 122880;          // 4096
  float* values = ws + 126976;          // 65536
  float* syncv  = ws + 192512;          // 1024
  float* scp    = ws + 193536;          // 64*512 = 32768
  float* sc     = ws + 226304;          // 512
  unsigned* bar = (unsigned*)(ws + 226816);  // 512 uints

  k_init<<<1, 512, 0, stream>>>(bar);
  k_enc<<<B_ / 2, 256, 0, stream>>>(x, ie_w1, ie_b1, ie_g1, ie_be1,
                                    ie_w2, ie_b2, ie_g2, ie_be2,
                                    ie_w3, ie_b3, val_w, val_b, enc, values);

  PArgs pa;
  pa.post0 = post0; pa.pre0 = pre0; pa.enc = enc;
  pa.syw1 = sy_w1; pa.syb1 = sy_b1; pa.syg = sy_g; pa.sybe = sy_be;
  pa.syw2 = sy_w2; pa.syb2 = sy_b2;
  pa.nw1 = nm_w1; pa.nb1 = nm_b1; pa.ng = nm_g; pa.nbe = nm_be;
  pa.nw2 = nm_w2; pa.nb2 = nm_b2;
  pa.pairs = pairs; pa.decay = decay;
  pa.rdw1 = rd_w1; pa.rdb1 = rd_b1;
  pa.pc = pc; pa.hb = hb; pa.postG = postG; pa.syncv = syncv;
  pa.scp = scp; pa.sc = sc; pa.bar = bar;
  k_persist<<<NBLK, NTHR, 0, stream>>>(pa);

  k_read<<<B_ / 4, 512, 0, stream>>>(values, sc, rd_w1, rd_g1, rd_be1,
                                     rd_w2, rd_b2, rd_g2, rd_be2, rd_w3, rd_b3, out);
}

// Round 7
// 212.495 us; speedup vs baseline: 12.9529x; 1.2452x over previous
//
#include <hip/hip_runtime.h>

#define N_ 4096
#define M_ 10
#define T_ 10
#define B_ 1024
#define P_ 1024
#define NBLK 256
#define NTHR 512

__device__ __forceinline__ float wave_red_sum(float v) {
#pragma unroll
  for (int m = 32; m >= 1; m >>= 1) v += __shfl_xor(v, m);
  return v;
}

// Agent-scope bypass accessors (served at coherence point; no cache-maintenance).
__device__ __forceinline__ float gld(const float* p) {
  return __hip_atomic_load(p, __ATOMIC_RELAXED, __HIP_MEMORY_SCOPE_AGENT);
}
__device__ __forceinline__ void gst(float* p, float v) {
  __hip_atomic_store(p, v, __ATOMIC_RELAXED, __HIP_MEMORY_SCOPE_AGENT);
}

// Monotonic relaxed-only grid barrier. Arrival: 8 stride-32 counters.
// Release: block0 publishes bar_no to 8 per-group gen copies (32 pollers/line).
__device__ __forceinline__ void gridbar(unsigned* bar, unsigned bar_no, int g) {
  asm volatile("s_waitcnt vmcnt(0)" ::: "memory");
  __syncthreads();
  if (threadIdx.x == 0) {
    __hip_atomic_fetch_add(&bar[(g & 7) * 32], 1u, __ATOMIC_RELAXED, __HIP_MEMORY_SCOPE_AGENT);
    if (g == 0) {
      const unsigned target = bar_no * (NBLK / 8);
      bool done;
      do {
        done = true;
#pragma unroll
        for (int i = 0; i < 8; ++i)
          done &= (__hip_atomic_load(&bar[i * 32], __ATOMIC_RELAXED, __HIP_MEMORY_SCOPE_AGENT) >= target);
        if (!done) __builtin_amdgcn_s_sleep(1);
      } while (!done);
#pragma unroll
      for (int i = 0; i < 8; ++i)
        __hip_atomic_store(&bar[256 + i * 32], bar_no, __ATOMIC_RELAXED, __HIP_MEMORY_SCOPE_AGENT);
    } else {
      unsigned* mygen = &bar[256 + (g & 7) * 32];
      while (__hip_atomic_load(mygen, __ATOMIC_RELAXED, __HIP_MEMORY_SCOPE_AGENT) < bar_no)
        __builtin_amdgcn_s_sleep(1);
    }
  }
  asm volatile("" ::: "memory");
  __syncthreads();
}

__global__ void k_init(unsigned* __restrict__ bar) {
  if (threadIdx.x < 512)
    __hip_atomic_store(bar + threadIdx.x, 0u, __ATOMIC_RELAXED, __HIP_MEMORY_SCOPE_AGENT);
}

struct MArgs {
  const float *x, *post0, *pre0;
  const int* pairs;
  const float* decay;
  const float *iew1, *ieb1, *ieg1, *iebe1, *iew2, *ieb2, *ieg2, *iebe2, *iew3, *ieb3;
  const float *syw1, *syb1, *syg, *sybe, *syw2, *syb2;
  const float *nw1, *nb1, *ng, *nbe, *nw2, *nb2;
  const float *vw, *vb;
  const float *rdw1, *rdb1, *rdg1, *rdbe1, *rdw2, *rdb2, *rdg2, *rdbe2, *rdw3, *rdb3;
  float *pc, *pc2, *enc_g, *hbar, *postG, *syncv, *scp;
  float* out;
  unsigned* bar;
};

// ONE persistent mega-kernel: encoder + T=10 recurrence + sync + readout.
// 256 blocks x 512 threads, 1 block/CU (LDS ~130 KB).
// Block g owns: neurons n in [16g,16g+16) (state + nm_w1/syw1 slices pinned in
// LDS); batch rows [4g,4g+4) for encoder + readout (values kept in LDS).
__global__ __launch_bounds__(NTHR)
void k_mega(MArgs a) {
  const int g = blockIdx.x, tid = threadIdx.x;
  const int lane = tid & 63;
  const int n0 = g * 16;
  const int b0e = g * 4;

  __shared__ float s_w1[16 * M_ * 128];   // 80 KB nm_w1 slice
  __shared__ float s_syw1[16 * 256];      // 16 KB sy_w1 rows 4+n0..
  __shared__ float s_w4[4 * 256];         // 4 KB sy_w1 rows 0..3
  __shared__ float scratch[6144];         // 24 KB multi-use
  __shared__ float s_post[16][M_];
  __shared__ float s_pre[16][M_];
  __shared__ float s_pl[16];
  __shared__ float s_hbar[256];
  __shared__ float s_cval[256];
  __shared__ float s_tmp[2][256];
  __shared__ float s_red[16];
  __shared__ float s_values[4][64];
  __shared__ float s_stat[6];
  __shared__ float s_mw[4];
  __shared__ float s_mww[16];

  unsigned bar_no = 0;

  // ================= PROLOGUE: pin weights, state, encoder, first pc ========
  {
    const float4* src = (const float4*)(a.nw1 + n0 * M_ * 128);
    float4* dst = (float4*)s_w1;
    for (int i = tid; i < 16 * M_ * 128 / 4; i += NTHR) dst[i] = src[i];
    const float4* s2 = (const float4*)(a.syw1 + (4 + n0) * 256);
    float4* d2 = (float4*)s_syw1;
    for (int i = tid; i < 16 * 256 / 4; i += NTHR) d2[i] = s2[i];
    const float4* s3 = (const float4*)a.syw1;
    float4* d3 = (float4*)s_w4;
    for (int i = tid; i < 1024 / 4; i += NTHR) d3[i] = s3[i];
    if (tid < 160) {
      int r = tid / 10, m = tid - r * 10;
      s_post[r][m] = a.post0[(n0 + r) * M_ + m];
      s_pre[r][m]  = a.pre0[(n0 + r) * M_ + m];
    }
    float* fx = scratch;  // [4][784]
    for (int i = tid; i < 4 * 784; i += NTHR) fx[i] = a.x[b0e * 784 + i];
  }
  __syncthreads();
  if (tid < 16) s_pl[tid] = s_post[tid][M_ - 1];

  // ---- encoder E1 (4 rows x 128): thread r=tid>>7, j=tid&127 ----
  {
    float* fx = scratch;
    float* e1 = scratch + 3200;  // [4][128]
    int r = tid >> 7, j = tid & 127;
    float u = a.ieb1[j];
    const float* fxr = fx + r * 784;
    for (int k = 0; k < 784; ++k) u += fxr[k] * a.iew1[k * 128 + j];
    float s = wave_red_sum(u), sq = wave_red_sum(u * u);
    int w = tid >> 6;
    if (lane == 0) { s_tmp[0][w] = s; s_tmp[1][w] = sq; }
    __syncthreads();
    float S = s_tmp[0][r * 2] + s_tmp[0][r * 2 + 1];
    float S2 = s_tmp[1][r * 2] + s_tmp[1][r * 2 + 1];
    float mm = S * (1.f / 128.f), vv = S2 * (1.f / 128.f) - mm * mm;
    e1[r * 128 + j] = fmaxf((u - mm) * rsqrtf(vv + 1e-5f) * a.ieg1[j] + a.iebe1[j], 0.f);
  }
  __syncthreads();
  {  // E2 (4 rows x 32), LN32 via width-32 shuffles
    float* e1 = scratch + 3200;
    float* e2 = scratch + 3712;  // [4][32]
    if (tid < 128) {
      int r = tid >> 5, jj = tid & 31;
      float u = a.ieb2[jj];
      for (int k = 0; k < 128; ++k) u += e1[r * 128 + k] * a.iew2[k * 32 + jj];
      float ss = u, sq = u * u;
#pragma unroll
      for (int m = 16; m >= 1; m >>= 1) { ss += __shfl_xor(ss, m, 32); sq += __shfl_xor(sq, m, 32); }
      float mm = ss * (1.f / 32.f), vv = sq * (1.f / 32.f) - mm * mm;
      e2[r * 32 + jj] = fmaxf((u - mm) * rsqrtf(vv + 1e-5f) * a.ieg2[jj] + a.iebe2[jj], 0.f);
    }
  }
  __syncthreads();
  {  // enc (4x4) -> enc_g bypass; values (4x64) -> LDS
    float* e2 = scratch + 3712;
    float* encs = scratch + 3840;  // [4][4]
    if (tid < 16) {
      int r = tid >> 2, o = tid & 3;
      float u = a.ieb3[o];
      for (int k = 0; k < 32; ++k) u += e2[r * 32 + k] * a.iew3[k * 4 + o];
      encs[r * 4 + o] = u;
      gst(&a.enc_g[(b0e + r) * 4 + o], u);
    }
    __syncthreads();
    if (tid < 256) {  // softmax over size-1 axis == 1 -> att == values
      int r = tid >> 6, v = tid & 63;
      float u = a.vb[v];
#pragma unroll
      for (int o = 0; o < 4; ++o) u += encs[r * 4 + o] * a.vw[o * 64 + v];
      s_values[r][v] = u;
    }
  }
  __syncthreads();
  {  // first pc partial (own 16 n)
    int j = tid & 255, half = tid >> 8;
    float acc = 0.f;
#pragma unroll
    for (int r = 0; r < 8; ++r) {
      int n = half * 8 + r;
      acc += s_pl[n] * s_syw1[n * 256 + j];
    }
    s_tmp[half][j] = acc;
  }
  __syncthreads();
  if (tid < 256) gst(&a.pc[g * 256 + tid], s_tmp[0][tid] + s_tmp[1][tid]);
  ++bar_no; gridbar(a.bar, bar_no, g);

  // ================= TICK LOOP ===============================================
  for (int t = 0; t < T_; ++t) {
    // ---- S1: blocks 0..7 pre-reduce pc rows (32 each) -> pc2[8][256] ----
    if (g < 8) {
      int j = tid & 255, half = tid >> 8;
      float acc = 0.f;
#pragma unroll 4
      for (int r = 0; r < 16; ++r)
        acc += gld(&a.pc[(g * 32 + half * 16 + r) * 256 + j]);
      s_tmp[half][j] = acc;
      __syncthreads();
      if (tid < 256) gst(&a.pc2[g * 256 + tid], s_tmp[0][tid] + s_tmp[1][tid]);
    }
    ++bar_no; gridbar(a.bar, bar_no, g);

    // ---- C: blocks 0..63: cval + analytic LN stats + hbar (4 cols each) ----
    if (g < 64) {
      float* encT = scratch;         // [4][1024]
      float* mb = scratch + 4096;    // [1024]
      float* rb = scratch + 5120;    // [1024]
      if (t == 0) {
        for (int i = tid; i < 4096; i += NTHR) {
          int b = i >> 2, o = i & 3;
          encT[o * 1024 + b] = gld(&a.enc_g[i]);
        }
        // static stats: mw[4], mww upper-tri (10)
        float q[14];
        if (tid < 256) {
          float w0 = s_w4[tid], w1v = s_w4[256 + tid], w2v = s_w4[512 + tid], w3v = s_w4[768 + tid];
          float wv[4] = {w0, w1v, w2v, w3v};
          int idx = 0;
#pragma unroll
          for (int o = 0; o < 4; ++o) q[idx++] = wv[o];
#pragma unroll
          for (int o = 0; o < 4; ++o)
#pragma unroll
            for (int p = 0; p <= o; ++p) q[idx++] = wv[o] * wv[p];
        } else {
#pragma unroll
          for (int i = 0; i < 14; ++i) q[i] = 0.f;
        }
#pragma unroll
        for (int i = 0; i < 14; ++i) q[i] = wave_red_sum(q[i]);
        if (lane == 0) {
          int w = tid >> 6;
#pragma unroll
          for (int i = 0; i < 14; ++i) s_tmp[1][w * 16 + i] = q[i];
        }
        __syncthreads();
        if (tid < 14) {
          float S = 0.f;
#pragma unroll
          for (int w = 0; w < 8; ++w) S += s_tmp[1][w * 16 + tid];
          s_red[tid] = S * (1.f / 256.f);
        }
        __syncthreads();
        if (tid < 4) s_mw[tid] = s_red[tid];
        if (tid < 16) {
          int o = tid >> 2, p = tid & 3;
          int hi = o > p ? o : p, lo = o > p ? p : o;
          s_mww[tid] = s_red[4 + hi * (hi + 1) / 2 + lo];
        }
        __syncthreads();
      }
      // cval[256] = syb1 + sum of pc2 strips
      if (tid < 256) {
        float acc = a.syb1[tid];
#pragma unroll
        for (int s = 0; s < 8; ++s) acc += gld(&a.pc2[s * 256 + tid]);
        s_cval[tid] = acc;
      }
      __syncthreads();
      // tick stats: mc, mcc, mcw[4]
      {
        float p[6];
        if (tid < 256) {
          float c = s_cval[tid];
          p[0] = c; p[1] = c * c;
          p[2] = c * s_w4[tid];
          p[3] = c * s_w4[256 + tid];
          p[4] = c * s_w4[512 + tid];
          p[5] = c * s_w4[768 + tid];
        } else {
#pragma unroll
          for (int i = 0; i < 6; ++i) p[i] = 0.f;
        }
#pragma unroll
        for (int i = 0; i < 6; ++i) p[i] = wave_red_sum(p[i]);
        if (lane == 0) {
          int w = tid >> 6;
#pragma unroll
          for (int i = 0; i < 6; ++i) s_tmp[0][w * 8 + i] = p[i];
        }
        __syncthreads();
        if (tid < 6) {
          float S = 0.f;
#pragma unroll
          for (int w = 0; w < 8; ++w) S += s_tmp[0][w * 8 + tid];
          s_stat[tid] = S * (1.f / 256.f);
        }
        __syncthreads();
      }
      // per-batch LN stats (replicated)
      for (int b = tid; b < 1024; b += NTHR) {
        float e0 = encT[b], e1v = encT[1024 + b], e2v = encT[2048 + b], e3v = encT[3072 + b];
        float m = s_stat[0] + e0 * s_mw[0] + e1v * s_mw[1] + e2v * s_mw[2] + e3v * s_mw[3];
        float eu2 = s_stat[1] + 2.f * (e0 * s_stat[2] + e1v * s_stat[3] + e2v * s_stat[4] + e3v * s_stat[5]);
        float ee[4] = {e0, e1v, e2v, e3v};
        float qf = 0.f;
#pragma unroll
        for (int o = 0; o < 4; ++o)
#pragma unroll
          for (int p = 0; p < 4; ++p) qf += ee[o] * ee[p] * s_mww[o * 4 + p];
        eu2 += qf;
        mb[b] = m;
        rb[b] = rsqrtf(eu2 - m * m + 1e-5f);
      }
      __syncthreads();
      // hbar for 4 columns: col jj = 4g + (tid>>7), 128 threads x 8 b each
      {
        int jj = 4 * g + (tid >> 7);
        int bt = tid & 127;
        float cj = s_cval[jj];
        float w0 = s_w4[jj], w1v = s_w4[256 + jj], w2v = s_w4[512 + jj], w3v = s_w4[768 + jj];
        float gj = a.syg[jj], bj = a.sybe[jj];
        float acc = 0.f;
#pragma unroll
        for (int bb = 0; bb < 8; ++bb) {
          int b = bb * 128 + bt;
          float u = cj + encT[b] * w0 + encT[1024 + b] * w1v + encT[2048 + b] * w2v + encT[3072 + b] * w3v;
          float y = (u - mb[b]) * rb[b] * gj + bj;
          acc += fmaxf(y, 0.f);
        }
        acc = wave_red_sum(acc);
        int w = tid >> 6;
        if (lane == 0) s_tmp[0][w] = acc;
        __syncthreads();
        if ((tid & 127) == 0)
          gst(&a.hbar[jj], (s_tmp[0][w] + s_tmp[0][w + 1]) * (1.f / 1024.f));
      }
    }
    ++bar_no; gridbar(a.bar, bar_no, g);

    // ---- P3: all blocks: pre update + nm + post shift + next pc ----
    {
      if (tid < 256) s_hbar[tid] = gld(&a.hbar[tid]);
      __syncthreads();
      {  // npre (own 16 n); s_tmp as [32][16]
        int nl = tid & 15, kq = tid >> 4;
        float u = 0.f;
#pragma unroll
        for (int kk = 0; kk < 8; ++kk) {
          int k = kq * 8 + kk;
          u += s_hbar[k] * a.syw2[k * N_ + n0 + nl];
        }
        ((float*)s_tmp)[kq * 16 + nl] = u;
      }
      __syncthreads();
      if (tid < 16) {
        float v = a.syb2[n0 + tid];
#pragma unroll
        for (int q = 0; q < 32; ++q) v += ((float*)s_tmp)[q * 16 + tid];
#pragma unroll
        for (int m = 0; m < M_ - 1; ++m) s_pre[tid][m] = s_pre[tid][m + 1];
        s_pre[tid][M_ - 1] = v;
      }
      __syncthreads();
      {  // nm: 4 rounds x 4 n
        int grp = tid >> 7, jj = tid & 127;
        int wv = tid >> 6;
#pragma unroll
        for (int rd = 0; rd < 4; ++rd) {
          int nl = rd * 4 + grp;
          int n2 = n0 + nl;
          float u = a.nb1[n2 * 128 + jj];
#pragma unroll
          for (int m = 0; m < M_; ++m) u += s_pre[nl][m] * s_w1[(nl * M_ + m) * 128 + jj];
          float s = wave_red_sum(u), sq = wave_red_sum(u * u);
          if (lane == 0) { s_red[wv * 2] = s; s_red[wv * 2 + 1] = sq; }
          __syncthreads();
          float S = s_red[grp * 4 + 0] + s_red[grp * 4 + 2];
          float S2 = s_red[grp * 4 + 1] + s_red[grp * 4 + 3];
          float mm = S * (1.f / 128.f), vv = S2 * (1.f / 128.f) - mm * mm;
          float y = fmaxf((u - mm) * rsqrtf(vv + 1e-5f) * a.ng[n2 * 128 + jj] + a.nbe[n2 * 128 + jj], 0.f);
          float d = wave_red_sum(y * a.nw2[n2 * 128 + jj]);
          __syncthreads();
          if (lane == 0) s_red[wv] = d;
          __syncthreads();
          if (jj == 0) {
            float npost = s_red[grp * 2] + s_red[grp * 2 + 1] + a.nb2[n2];
#pragma unroll
            for (int m = 0; m < M_ - 1; ++m) s_post[nl][m] = s_post[nl][m + 1];
            s_post[nl][M_ - 1] = npost;
            s_pl[nl] = npost;
          }
          __syncthreads();
        }
      }
      if (t < T_ - 1) {  // next pc
        int j = tid & 255, half = tid >> 8;
        float acc = 0.f;
#pragma unroll
        for (int r = 0; r < 8; ++r) {
          int n = half * 8 + r;
          acc += s_pl[n] * s_syw1[n * 256 + j];
        }
        s_tmp[half][j] = acc;
        __syncthreads();
        if (tid < 256) gst(&a.pc[g * 256 + tid], s_tmp[0][tid] + s_tmp[1][tid]);
      } else {  // flush final post rows
        if (tid < 160) {
          int r = tid / 10, m = tid - r * 10;
          gst(&a.postG[(n0 + r) * M_ + m], s_post[r][m]);
        }
      }
    }
    ++bar_no; gridbar(a.bar, bar_no, g);
  }

  // ================= EPILOGUE ================================================
  // syncv: 4 pairs per block (tick 9 => L = M, full rows)
  if (tid < 4) {
    int p = g * 4 + tid;
    int i = a.pairs[p * 2], jn = a.pairs[p * 2 + 1];
    float dc = a.decay[p];
    float num = 0.f, den = 0.f;
#pragma unroll
    for (int l = 0; l < M_; ++l) {
      float r = expf(-dc * (float)(M_ - 1 - l));
      num += gld(&a.postG[i * M_ + l]) * r * gld(&a.postG[jn * M_ + l]);
      den += r;
    }
    gst(&a.syncv[p], num / (den + 1e-8f));
  }
  ++bar_no; gridbar(a.bar, bar_no, g);

  // scp: blocks 0..7, 128-p chunk x 512 j
  if (g < 8) {
    if (tid < 128) s_tmp[0][tid] = gld(&a.syncv[g * 128 + tid]);
    __syncthreads();
    float acc = 0.f;
    for (int i = 0; i < 128; ++i)
      acc += s_tmp[0][i] * a.rdw1[(64 + g * 128 + i) * 512 + tid];
    gst(&a.scp[g * 512 + tid], acc);
  }
  ++bar_no; gridbar(a.bar, bar_no, g);

  // readout for own 4 batch rows (values in LDS)
  {
    float* r1 = scratch;          // [4][512]
    float* r2 = scratch + 2048;   // [4][64]
    float* red = scratch + 2304;  // [4][16]
    float* p2 = scratch + 2368;   // [8][4][64]
    float base = a.rdb1[tid];
#pragma unroll
    for (int s = 0; s < 8; ++s) base += gld(&a.scp[s * 512 + tid]);
    float u[4];
#pragma unroll
    for (int r = 0; r < 4; ++r) u[r] = base;
    for (int k = 0; k < 64; ++k) {
      float w = a.rdw1[k * 512 + tid];
#pragma unroll
      for (int r = 0; r < 4; ++r) u[r] += s_values[r][k] * w;
    }
    int wid = tid >> 6;
#pragma unroll
    for (int r = 0; r < 4; ++r) {
      float s = wave_red_sum(u[r]), sq = wave_red_sum(u[r] * u[r]);
      if (lane == 0) { red[r * 16 + wid * 2] = s; red[r * 16 + wid * 2 + 1] = sq; }
    }
    __syncthreads();
    float gg = a.rdg1[tid], bb = a.rdbe1[tid];
#pragma unroll
    for (int r = 0; r < 4; ++r) {
      float S = 0.f, S2 = 0.f;
#pragma unroll
      for (int w = 0; w < 8; ++w) { S += red[r * 16 + w * 2]; S2 += red[r * 16 + w * 2 + 1]; }
      float m = S * (1.f / 512.f), v = S2 * (1.f / 512.f) - m * m;
      r1[r * 512 + tid] = fmaxf((u[r] - m) * rsqrtf(v + 1e-5f) * gg + bb, 0.f);
    }
    __syncthreads();
    int o = tid & 63, kq = tid >> 6;
    float u2[4] = {0.f, 0.f, 0.f, 0.f};
#pragma unroll
    for (int kk = 0; kk < 64; ++kk) {
      int k = kq * 64 + kk;
      float w = a.rdw2[k * 64 + o];
#pragma unroll
      for (int r = 0; r < 4; ++r) u2[r] += r1[r * 512 + k] * w;
    }
#pragma unroll
    for (int r = 0; r < 4; ++r) p2[(kq * 4 + r) * 64 + o] = u2[r];
    __syncthreads();
    if (tid < 256) {
      int r = tid >> 6, o2 = tid & 63;
      float v = a.rdb2[o2];
#pragma unroll
      for (int q = 0; q < 8; ++q) v += p2[(q * 4 + r) * 64 + o2];
      float s = wave_red_sum(v), sq = wave_red_sum(v * v);
      float m = s * (1.f / 64.f), var = sq * (1.f / 64.f) - m * m;
      r2[r * 64 + o2] = fmaxf((v - m) * rsqrtf(var + 1e-5f) * a.rdg2[o2] + a.rdbe2[o2], 0.f);
    }
    __syncthreads();
    if (tid < 40) {
      int r = tid / 10, o3 = tid - r * 10;
      float acc = a.rdb3[o3];
#pragma unroll
      for (int k = 0; k < 64; ++k) acc += r2[r * 64 + k] * a.rdw3[k * 10 + o3];
      a.out[(b0e + r) * 10 + o3] = acc;
    }
  }
}

extern "C" void kernel_launch(void* const* d_in, const int* in_sizes, int n_in,
                              void* d_out, int out_size, void* d_ws, size_t ws_size,
                              hipStream_t stream) {
  MArgs a;
  a.x     = (const float*)d_in[0];
  a.post0 = (const float*)d_in[1];
  a.pre0  = (const float*)d_in[2];
  a.pairs = (const int*)d_in[3];
  a.decay = (const float*)d_in[4];
  a.iew1  = (const float*)d_in[5];
  a.ieb1  = (const float*)d_in[6];
  a.ieg1  = (const float*)d_in[7];
  a.iebe1 = (const float*)d_in[8];
  a.iew2  = (const float*)d_in[9];
  a.ieb2  = (const float*)d_in[10];
  a.ieg2  = (const float*)d_in[11];
  a.iebe2 = (const float*)d_in[12];
  a.iew3  = (const float*)d_in[13];
  a.ieb3  = (const float*)d_in[14];
  a.syw1  = (const float*)d_in[15];
  a.syb1  = (const float*)d_in[16];
  a.syg   = (const float*)d_in[17];
  a.sybe  = (const float*)d_in[18];
  a.syw2  = (const float*)d_in[19];
  a.syb2  = (const float*)d_in[20];
  a.nw1   = (const float*)d_in[21];
  a.nb1   = (const float*)d_in[22];
  a.ng    = (const float*)d_in[23];
  a.nbe   = (const float*)d_in[24];
  a.nw2   = (const float*)d_in[25];
  a.nb2   = (const float*)d_in[26];
  a.vw    = (const float*)d_in[29];
  a.vb    = (const float*)d_in[30];
  a.rdw1  = (const float*)d_in[33];
  a.rdb1  = (const float*)d_in[34];
  a.rdg1  = (const float*)d_in[35];
  a.rdbe1 = (const float*)d_in[36];
  a.rdw2  = (const float*)d_in[37];
  a.rdb2  = (const float*)d_in[38];
  a.rdg2  = (const float*)d_in[39];
  a.rdbe2 = (const float*)d_in[40];
  a.rdw3  = (const float*)d_in[41];
  a.rdb3  = (const float*)d_in[42];
  a.out = (float*)d_out;

  float* ws = (float*)d_ws;
  a.pc    = ws;             // 65536
  a.pc2   = ws + 65536;     // 2048
  a.enc_g = ws + 67584;     // 4096
  a.hbar  = ws + 71680;     // 256
  a.postG = ws + 71936;     // 40960
  a.syncv = ws + 112896;    // 1024
  a.scp   = ws + 113920;    // 4096
  a.bar   = (unsigned*)(ws + 118016);  // 512 uints

  k_init<<<1, 512, 0, stream>>>(a.bar);
  k_mega<<<NBLK, NTHR, 0, stream>>>(a);
}

// Round 8
// 197.953 us; speedup vs baseline: 13.9045x; 1.0735x over previous
//
#include <hip/hip_runtime.h>

#define N_ 4096
#define M_ 10
#define T_ 10
#define B_ 1024
#define P_ 1024
#define NBLK 256
#define NTHR 512

__device__ __forceinline__ float wave_red_sum(float v) {
#pragma unroll
  for (int m = 32; m >= 1; m >>= 1) v += __shfl_xor(v, m);
  return v;
}

// Agent-scope bypass accessors (coherence-point served; no cache maintenance).
__device__ __forceinline__ float gld(const float* p) {
  return __hip_atomic_load(p, __ATOMIC_RELAXED, __HIP_MEMORY_SCOPE_AGENT);
}
__device__ __forceinline__ void gst(float* p, float v) {
  __hip_atomic_store(p, v, __ATOMIC_RELAXED, __HIP_MEMORY_SCOPE_AGENT);
}
__device__ __forceinline__ unsigned ld_u(unsigned* p) {
  return __hip_atomic_load(p, __ATOMIC_RELAXED, __HIP_MEMORY_SCOPE_AGENT);
}

// All prior bypass stores drained (per-wave vmcnt) before any signal.
__device__ __forceinline__ void drain_sync() {
  asm volatile("s_waitcnt vmcnt(0)" ::: "memory");
  __syncthreads();
}
__device__ __forceinline__ void arrive8(unsigned* line8, int g) {
  if (threadIdx.x == 0)
    __hip_atomic_fetch_add(&line8[(g & 7) * 32], 1u, __ATOMIC_RELAXED, __HIP_MEMORY_SCOPE_AGENT);
}
__device__ __forceinline__ void wait_sum8(unsigned* line8, unsigned target) {
  if (threadIdx.x == 0) {
    unsigned s;
    do {
      s = 0;
#pragma unroll
      for (int i = 0; i < 8; ++i) s += ld_u(&line8[i * 32]);
      if (s < target) __builtin_amdgcn_s_sleep(1);
    } while (s < target);
  }
  __syncthreads();
}
__device__ __forceinline__ void wait_word(unsigned* f, unsigned target) {
  if (threadIdx.x == 0) {
    while (ld_u(f) < target) __builtin_amdgcn_s_sleep(1);
  }
  __syncthreads();
}

__global__ void k_init(unsigned* __restrict__ bar) {
  if (threadIdx.x < 1024)
    __hip_atomic_store(bar + threadIdx.x, 0u, __ATOMIC_RELAXED, __HIP_MEMORY_SCOPE_AGENT);
}

struct MArgs {
  const float *x, *post0, *pre0;
  const int* pairs;
  const float* decay;
  const float *iew1, *ieb1, *ieg1, *iebe1, *iew2, *ieb2, *ieg2, *iebe2, *iew3, *ieb3;
  const float *syw1, *syb1, *syg, *sybe, *syw2, *syb2;
  const float *nw1, *nb1, *ng, *nbe, *nw2, *nb2;
  const float *vw, *vb;
  const float *rdw1, *rdb1, *rdg1, *rdbe1, *rdw2, *rdb2, *rdg2, *rdbe2, *rdw3, *rdb3;
  float *pc, *pc2, *enc_g, *hbar, *postG, *syncv, *scp, *cstat;
  float* out;
  unsigned* bar;
};

// ONE persistent mega-kernel. 256 blocks x 512 threads, 1 block/CU.
// Block g owns neurons [16g,16g+16) (nm_w1/syw1 slices pinned in LDS) and
// batch rows [4g,4g+4) (encoder + readout; values stay in LDS).
// Tick sync: counterA (all 256, after pc) -> strips (g<8) -> counterR ->
// block0 (cval+stats) -> flagB -> C blocks (g<64: mb/rb + 4 hbar cols) ->
// counterC -> everyone.
__global__ __launch_bounds__(NTHR)
void k_mega(MArgs a) {
  const int g = blockIdx.x, tid = threadIdx.x;
  const int lane = tid & 63;
  const int n0 = g * 16, b0e = g * 4;

  __shared__ float s_w1[16 * M_ * 128];   // 80 KB nm_w1 slice
  __shared__ float s_syw1[16 * 256];      // 16 KB sy_w1 rows 4+n0..
  __shared__ float s_w4[4 * 256];         // 4 KB sy_w1 rows 0..3
  __shared__ float reg1[4096];            // fx | encT | r1+p2
  __shared__ float reg2[1024];            // e1/e2/encs | r2
  __shared__ float s_mbrb[2048];          // mb[1024], rb[1024] (C blocks)
  __shared__ float s_values[4][64];
  __shared__ float s_post[16][M_];
  __shared__ float s_pre[16][M_];
  __shared__ float s_pl[16];
  __shared__ float s_hbar[256];
  __shared__ float s_tmp[2][256];
  __shared__ float s_red[16];
  __shared__ float s_stats[20];
  __shared__ float s_static[14];

  unsigned* barA = a.bar;          // 8 lines stride 32
  unsigned* barC = a.bar + 256;    // 8 lines stride 32
  unsigned* barR = a.bar + 512;    // single word
  unsigned* flagB = a.bar + 544;   // single word

  // ================= PROLOGUE ===============================================
  {
    const float4* src = (const float4*)(a.nw1 + n0 * M_ * 128);
    float4* dst = (float4*)s_w1;
    for (int i = tid; i < 16 * M_ * 128 / 4; i += NTHR) dst[i] = src[i];
    const float4* s2 = (const float4*)(a.syw1 + (4 + n0) * 256);
    float4* d2 = (float4*)s_syw1;
    for (int i = tid; i < 16 * 256 / 4; i += NTHR) d2[i] = s2[i];
    const float4* s3 = (const float4*)a.syw1;
    float4* d3 = (float4*)s_w4;
    for (int i = tid; i < 1024 / 4; i += NTHR) d3[i] = s3[i];
    if (tid < 160) {
      int r = tid / 10, m = tid - r * 10;
      s_post[r][m] = a.post0[(n0 + r) * M_ + m];
      s_pre[r][m]  = a.pre0[(n0 + r) * M_ + m];
    }
    for (int i = tid; i < 4 * 784; i += NTHR) reg1[i] = a.x[b0e * 784 + i];
  }
  __syncthreads();
  if (tid < 16) s_pl[tid] = s_post[tid][M_ - 1];

  {  // encoder E1: 4 rows x 128 j
    int r = tid >> 7, j = tid & 127;
    float u = a.ieb1[j];
    const float* fxr = reg1 + r * 784;
    for (int k = 0; k < 784; ++k) u += fxr[k] * a.iew1[k * 128 + j];
    float s = wave_red_sum(u), sq = wave_red_sum(u * u);
    int w = tid >> 6;
    if (lane == 0) { s_tmp[0][w] = s; s_tmp[1][w] = sq; }
    __syncthreads();
    float S = s_tmp[0][r * 2] + s_tmp[0][r * 2 + 1];
    float S2 = s_tmp[1][r * 2] + s_tmp[1][r * 2 + 1];
    float mm = S * (1.f / 128.f), vv = S2 * (1.f / 128.f) - mm * mm;
    reg2[r * 128 + j] = fmaxf((u - mm) * rsqrtf(vv + 1e-5f) * a.ieg1[j] + a.iebe1[j], 0.f);
  }
  __syncthreads();
  if (tid < 128) {  // E2: 4 rows x 32, LN32 via width-32 shuffles
    int r = tid >> 5, jj = tid & 31;
    float u = a.ieb2[jj];
    for (int k = 0; k < 128; ++k) u += reg2[r * 128 + k] * a.iew2[k * 32 + jj];
    float ss = u, sq = u * u;
#pragma unroll
    for (int m = 16; m >= 1; m >>= 1) { ss += __shfl_xor(ss, m, 32); sq += __shfl_xor(sq, m, 32); }
    float mm = ss * (1.f / 32.f), vv = sq * (1.f / 32.f) - mm * mm;
    reg2[512 + r * 32 + jj] = fmaxf((u - mm) * rsqrtf(vv + 1e-5f) * a.ieg2[jj] + a.iebe2[jj], 0.f);
  }
  __syncthreads();
  if (tid < 16) {  // enc 4x4
    int r = tid >> 2, o = tid & 3;
    float u = a.ieb3[o];
    for (int k = 0; k < 32; ++k) u += reg2[512 + r * 32 + k] * a.iew3[k * 4 + o];
    reg2[640 + r * 4 + o] = u;
    gst(&a.enc_g[(b0e + r) * 4 + o], u);
  }
  __syncthreads();
  if (tid < 256) {  // values (softmax over size-1 axis == 1 -> att == values)
    int r = tid >> 6, v = tid & 63;
    float u = a.vb[v];
#pragma unroll
    for (int o = 0; o < 4; ++o) u += reg2[640 + r * 4 + o] * a.vw[o * 64 + v];
    s_values[r][v] = u;
  }
  __syncthreads();
  {  // first pc partial
    int j = tid & 255, half = tid >> 8;
    float acc = 0.f;
#pragma unroll
    for (int r = 0; r < 8; ++r) {
      int n = half * 8 + r;
      acc += s_pl[n] * s_syw1[n * 256 + j];
    }
    s_tmp[half][j] = acc;
  }
  __syncthreads();
  if (tid < 256) gst(&a.pc[g * 256 + tid], s_tmp[0][tid] + s_tmp[1][tid]);
  drain_sync();
  arrive8(barA, g);

  // ================= TICK LOOP ==============================================
  for (int t = 0; t < T_; ++t) {
    // strips: blocks 0..7 reduce 32 pc rows each -> pc2
    if (g < 8) {
      wait_sum8(barA, 256u * (unsigned)(t + 1));
      int j = tid & 255, half = tid >> 8;
      float acc = 0.f;
#pragma unroll
      for (int r = 0; r < 16; ++r)
        acc += gld(&a.pc[(g * 32 + half * 16 + r) * 256 + j]);
      s_tmp[half][j] = acc;
      __syncthreads();
      if (tid < 256) gst(&a.pc2[g * 256 + tid], s_tmp[0][tid] + s_tmp[1][tid]);
      drain_sync();
      if (tid == 0)
        __hip_atomic_fetch_add(barR, 1u, __ATOMIC_RELAXED, __HIP_MEMORY_SCOPE_AGENT);
    }
    // block0: cval + stats
    if (g == 0) {
      wait_word(barR, 8u * (unsigned)(t + 1));
      float cv = 0.f;
      if (tid < 256) {
        cv = a.syb1[tid];
#pragma unroll
        for (int s = 0; s < 8; ++s) cv += gld(&a.pc2[s * 256 + tid]);
      }
      if (t == 0) {  // static w4 moments
        float q[14];
        if (tid < 256) {
          float wv[4] = {s_w4[tid], s_w4[256 + tid], s_w4[512 + tid], s_w4[768 + tid]};
          int idx = 0;
#pragma unroll
          for (int o = 0; o < 4; ++o) q[idx++] = wv[o];
#pragma unroll
          for (int o = 0; o < 4; ++o)
#pragma unroll
            for (int p = 0; p <= o; ++p) q[idx++] = wv[o] * wv[p];
        } else {
#pragma unroll
          for (int i = 0; i < 14; ++i) q[i] = 0.f;
        }
#pragma unroll
        for (int i = 0; i < 14; ++i) q[i] = wave_red_sum(q[i]);
        int w = tid >> 6;
        if (lane == 0) {
#pragma unroll
          for (int i = 0; i < 14; ++i) s_tmp[1][w * 16 + i] = q[i];
        }
        __syncthreads();
        if (tid < 14) {
          float S = 0.f;
#pragma unroll
          for (int w2 = 0; w2 < 8; ++w2) S += s_tmp[1][w2 * 16 + tid];
          s_static[tid] = S * (1.f / 256.f);
        }
        __syncthreads();
      }
      {  // tick stats: mc, mcc, mcw[4]
        float p[6];
        if (tid < 256) {
          p[0] = cv; p[1] = cv * cv;
          p[2] = cv * s_w4[tid]; p[3] = cv * s_w4[256 + tid];
          p[4] = cv * s_w4[512 + tid]; p[5] = cv * s_w4[768 + tid];
        } else {
#pragma unroll
          for (int i = 0; i < 6; ++i) p[i] = 0.f;
        }
#pragma unroll
        for (int i = 0; i < 6; ++i) p[i] = wave_red_sum(p[i]);
        int w = tid >> 6;
        if (lane == 0) {
#pragma unroll
          for (int i = 0; i < 6; ++i) s_tmp[0][w * 8 + i] = p[i];
        }
        __syncthreads();
        if (tid < 6) {
          float S = 0.f;
#pragma unroll
          for (int w2 = 0; w2 < 8; ++w2) S += s_tmp[0][w2 * 8 + tid];
          gst(&a.cstat[256 + tid], S * (1.f / 256.f));
        }
      }
      if (tid < 256) gst(&a.cstat[tid], cv);
      if (tid < 14) gst(&a.cstat[262 + tid], s_static[tid]);
      drain_sync();
      if (tid == 0)
        __hip_atomic_store(flagB, (unsigned)(t + 1), __ATOMIC_RELAXED, __HIP_MEMORY_SCOPE_AGENT);
    }
    // C blocks: mb/rb (redundant, cheap) + hbar for 4 columns
    if (g < 64) {
      wait_word(flagB, (unsigned)(t + 1));
      if (t == 0) {  // fill encT[4][1024] once
        for (int i = tid; i < 4096; i += NTHR) {
          int b = i >> 2, o = i & 3;
          reg1[o * 1024 + b] = gld(&a.enc_g[i]);
        }
      }
      if (tid < 20) s_stats[tid] = gld(&a.cstat[256 + tid]);
      if (tid < 4)  s_red[tid] = gld(&a.cstat[4 * g + tid]);
      __syncthreads();
      for (int b = tid; b < 1024; b += NTHR) {
        float e0 = reg1[b], e1v = reg1[1024 + b], e2v = reg1[2048 + b], e3v = reg1[3072 + b];
        float m = s_stats[0] + e0 * s_stats[6] + e1v * s_stats[7] + e2v * s_stats[8] + e3v * s_stats[9];
        float eu2 = s_stats[1] + 2.f * (e0 * s_stats[2] + e1v * s_stats[3] + e2v * s_stats[4] + e3v * s_stats[5]);
        float qf = e0 * e0 * s_stats[10]
                 + 2.f * e1v * e0 * s_stats[11] + e1v * e1v * s_stats[12]
                 + 2.f * e2v * e0 * s_stats[13] + 2.f * e2v * e1v * s_stats[14] + e2v * e2v * s_stats[15]
                 + 2.f * e3v * e0 * s_stats[16] + 2.f * e3v * e1v * s_stats[17]
                 + 2.f * e3v * e2v * s_stats[18] + e3v * e3v * s_stats[19];
        eu2 += qf;
        s_mbrb[b] = m;
        s_mbrb[1024 + b] = rsqrtf(eu2 - m * m + 1e-5f);
      }
      __syncthreads();
      {
        int q = tid >> 7, bt = tid & 127;
        int jj = 4 * g + q;
        float cj = s_red[q];
        float w0 = s_w4[jj], w1v = s_w4[256 + jj], w2v = s_w4[512 + jj], w3v = s_w4[768 + jj];
        float gj = a.syg[jj], bj = a.sybe[jj];
        float acc = 0.f;
#pragma unroll
        for (int bb = 0; bb < 8; ++bb) {
          int b = bb * 128 + bt;
          float u = cj + reg1[b] * w0 + reg1[1024 + b] * w1v + reg1[2048 + b] * w2v + reg1[3072 + b] * w3v;
          float y = (u - s_mbrb[b]) * s_mbrb[1024 + b] * gj + bj;
          acc += fmaxf(y, 0.f);
        }
        acc = wave_red_sum(acc);
        int wv = tid >> 6;
        if (lane == 0) s_tmp[0][wv] = acc;
        __syncthreads();
        if ((tid & 127) == 0)
          gst(&a.hbar[jj], (s_tmp[0][wv] + s_tmp[0][wv + 1]) * (1.f / 1024.f));
      }
      drain_sync();
      arrive8(barC, g);
    }
    // everyone: wait hbar, then P3
    wait_sum8(barC, 64u * (unsigned)(t + 1));
    if (tid < 256) s_hbar[tid] = gld(&a.hbar[tid]);
    __syncthreads();
    {  // npre: s_tmp as [32][16]
      int nl = tid & 15, kq = tid >> 4;
      float u = 0.f;
#pragma unroll
      for (int kk = 0; kk < 8; ++kk) {
        int k = kq * 8 + kk;
        u += s_hbar[k] * a.syw2[k * N_ + n0 + nl];
      }
      ((float*)s_tmp)[kq * 16 + nl] = u;
    }
    __syncthreads();
    if (tid < 16) {
      float v = a.syb2[n0 + tid];
#pragma unroll
      for (int q2 = 0; q2 < 32; ++q2) v += ((float*)s_tmp)[q2 * 16 + tid];
#pragma unroll
      for (int m = 0; m < M_ - 1; ++m) s_pre[tid][m] = s_pre[tid][m + 1];
      s_pre[tid][M_ - 1] = v;
    }
    __syncthreads();
    {  // nm one-pass: 16 neurons x 32 lanes, LN via width-32 shuffles
      int nl = tid >> 5, q = tid & 31;
      int n2 = n0 + nl;
      float pr[M_];
#pragma unroll
      for (int m = 0; m < M_; ++m) pr[m] = s_pre[nl][m];
      float u[4];
#pragma unroll
      for (int k = 0; k < 4; ++k) {
        int j = q + 32 * k;
        float uu = a.nb1[n2 * 128 + j];
#pragma unroll
        for (int m = 0; m < M_; ++m) uu += pr[m] * s_w1[(nl * M_ + m) * 128 + j];
        u[k] = uu;
      }
      float s = u[0] + u[1] + u[2] + u[3];
      float sq = u[0] * u[0] + u[1] * u[1] + u[2] * u[2] + u[3] * u[3];
#pragma unroll
      for (int m = 16; m >= 1; m >>= 1) { s += __shfl_xor(s, m, 32); sq += __shfl_xor(sq, m, 32); }
      float mm = s * (1.f / 128.f), vv = sq * (1.f / 128.f) - mm * mm;
      float ri = rsqrtf(vv + 1e-5f);
      float d = 0.f;
#pragma unroll
      for (int k = 0; k < 4; ++k) {
        int j = q + 32 * k;
        float y = fmaxf((u[k] - mm) * ri * a.ng[n2 * 128 + j] + a.nbe[n2 * 128 + j], 0.f);
        d += y * a.nw2[n2 * 128 + j];
      }
#pragma unroll
      for (int m = 16; m >= 1; m >>= 1) d += __shfl_xor(d, m, 32);
      if (q == 0) {
        float npost = d + a.nb2[n2];
#pragma unroll
        for (int m = 0; m < M_ - 1; ++m) s_post[nl][m] = s_post[nl][m + 1];
        s_post[nl][M_ - 1] = npost;
        s_pl[nl] = npost;
      }
    }
    __syncthreads();
    if (t < T_ - 1) {  // next pc partial
      int j = tid & 255, half = tid >> 8;
      float acc = 0.f;
#pragma unroll
      for (int r = 0; r < 8; ++r) {
        int n = half * 8 + r;
        acc += s_pl[n] * s_syw1[n * 256 + j];
      }
      s_tmp[half][j] = acc;
      __syncthreads();
      if (tid < 256) gst(&a.pc[g * 256 + tid], s_tmp[0][tid] + s_tmp[1][tid]);
    } else {  // flush final post rows
      if (tid < 160) {
        int r = tid / 10, m = tid - r * 10;
        gst(&a.postG[(n0 + r) * M_ + m], s_post[r][m]);
      }
    }
    drain_sync();
    arrive8(barA, g);
  }

  // ================= EPILOGUE ===============================================
  wait_sum8(barA, 256u * 11u);  // all postG visible
  if (tid < 4) {  // syncv: 4 pairs per block (tick 9 => L = M, full rows)
    int p = g * 4 + tid;
    int i = a.pairs[p * 2], jn = a.pairs[p * 2 + 1];
    float dc = a.decay[p];
    float num = 0.f, den = 0.f;
#pragma unroll
    for (int l = 0; l < M_; ++l) {
      float r = expf(-dc * (float)(M_ - 1 - l));
      num += gld(&a.postG[i * M_ + l]) * r * gld(&a.postG[jn * M_ + l]);
      den += r;
    }
    gst(&a.syncv[p], num / (den + 1e-8f));
  }
  drain_sync();
  arrive8(barA, g);  // -> 256*12
  if (g < 8) {       // scp strips
    wait_sum8(barA, 256u * 12u);
    if (tid < 128) s_tmp[0][tid] = gld(&a.syncv[g * 128 + tid]);
    __syncthreads();
    float acc = 0.f;
    for (int i = 0; i < 128; ++i)
      acc += s_tmp[0][i] * a.rdw1[(64 + g * 128 + i) * 512 + tid];
    gst(&a.scp[g * 512 + tid], acc);
    drain_sync();
    arrive8(barC, g);  // -> 640 + 8
  }
  wait_sum8(barC, 64u * 10u + 8u);
  {  // readout for own 4 batch rows
    float* r1 = reg1;
    float* p2 = reg1 + 2048;
    float base = a.rdb1[tid];
#pragma unroll
    for (int s = 0; s < 8; ++s) base += gld(&a.scp[s * 512 + tid]);
    float u[4];
#pragma unroll
    for (int r = 0; r < 4; ++r) u[r] = base;
    for (int k = 0; k < 64; ++k) {
      float w = a.rdw1[k * 512 + tid];
#pragma unroll
      for (int r = 0; r < 4; ++r) u[r] += s_values[r][k] * w;
    }
    int wid = tid >> 6;
#pragma unroll
    for (int r = 0; r < 4; ++r) {
      float s = wave_red_sum(u[r]), sq = wave_red_sum(u[r] * u[r]);
      if (lane == 0) { s_tmp[0][r * 8 + wid] = s; s_tmp[1][r * 8 + wid] = sq; }
    }
    __syncthreads();
    float gg = a.rdg1[tid], bb = a.rdbe1[tid];
#pragma unroll
    for (int r = 0; r < 4; ++r) {
      float S = 0.f, S2 = 0.f;
#pragma unroll
      for (int w = 0; w < 8; ++w) { S += s_tmp[0][r * 8 + w]; S2 += s_tmp[1][r * 8 + w]; }
      float m = S * (1.f / 512.f), v = S2 * (1.f / 512.f) - m * m;
      r1[r * 512 + tid] = fmaxf((u[r] - m) * rsqrtf(v + 1e-5f) * gg + bb, 0.f);
    }
    __syncthreads();
    int o = tid & 63, kq = tid >> 6;
    float u2[4] = {0.f, 0.f, 0.f, 0.f};
#pragma unroll
    for (int kk = 0; kk < 64; ++kk) {
      int k = kq * 64 + kk;
      float w = a.rdw2[k * 64 + o];
#pragma unroll
      for (int r = 0; r < 4; ++r) u2[r] += r1[r * 512 + k] * w;
    }
#pragma unroll
    for (int r = 0; r < 4; ++r) p2[(kq * 4 + r) * 64 + o] = u2[r];
    __syncthreads();
    if (tid < 256) {
      int r = tid >> 6, o2 = tid & 63;
      float v = a.rdb2[o2];
#pragma unroll
      for (int q = 0; q < 8; ++q) v += p2[(q * 4 + r) * 64 + o2];
      float s = wave_red_sum(v), sq = wave_red_sum(v * v);
      float m = s * (1.f / 64.f), var = sq * (1.f / 64.f) - m * m;
      reg2[r * 64 + o2] = fmaxf((v - m) * rsqrtf(var + 1e-5f) * a.rdg2[o2] + a.rdbe2[o2], 0.f);
    }
    __syncthreads();
    if (tid < 40) {
      int r = tid / 10, o3 = tid - r * 10;
      float acc = a.rdb3[o3];
#pragma unroll
      for (int k = 0; k < 64; ++k) acc += reg2[r * 64 + k] * a.rdw3[k * 10 + o3];
      a.out[(b0e + r) * 10 + o3] = acc;
    }
  }
}

extern "C" void kernel_launch(void* const* d_in, const int* in_sizes, int n_in,
                              void* d_out, int out_size, void* d_ws, size_t ws_size,
                              hipStream_t stream) {
  MArgs a;
  a.x     = (const float*)d_in[0];
  a.post0 = (const float*)d_in[1];
  a.pre0  = (const float*)d_in[2];
  a.pairs = (const int*)d_in[3];
  a.decay = (const float*)d_in[4];
  a.iew1  = (const float*)d_in[5];
  a.ieb1  = (const float*)d_in[6];
  a.ieg1  = (const float*)d_in[7];
  a.iebe1 = (const float*)d_in[8];
  a.iew2  = (const float*)d_in[9];
  a.ieb2  = (const float*)d_in[10];
  a.ieg2  = (const float*)d_in[11];
  a.iebe2 = (const float*)d_in[12];
  a.iew3  = (const float*)d_in[13];
  a.ieb3  = (const float*)d_in[14];
  a.syw1  = (const float*)d_in[15];
  a.syb1  = (const float*)d_in[16];
  a.syg   = (const float*)d_in[17];
  a.sybe  = (const float*)d_in[18];
  a.syw2  = (const float*)d_in[19];
  a.syb2  = (const float*)d_in[20];
  a.nw1   = (const float*)d_in[21];
  a.nb1   = (const float*)d_in[22];
  a.ng    = (const float*)d_in[23];
  a.nbe   = (const float*)d_in[24];
  a.nw2   = (const float*)d_in[25];
  a.nb2   = (const float*)d_in[26];
  a.vw    = (const float*)d_in[29];
  a.vb    = (const float*)d_in[30];
  a.rdw1  = (const float*)d_in[33];
  a.rdb1  = (const float*)d_in[34];
  a.rdg1  = (const float*)d_in[35];
  a.rdbe1 = (const float*)d_in[36];
  a.rdw2  = (const float*)d_in[37];
  a.rdb2  = (const float*)d_in[38];
  a.rdg2  = (const float*)d_in[39];
  a.rdbe2 = (const float*)d_in[40];
  a.rdw3  = (const float*)d_in[41];
  a.rdb3  = (const float*)d_in[42];
  a.out = (float*)d_out;

  float* ws = (float*)d_ws;
  a.pc    = ws;                 // 65536
  a.pc2   = ws + 65536;         // 2048
  a.enc_g = ws + 67584;         // 4096
  a.hbar  = ws + 71680;         // 256
  a.postG = ws + 71936;         // 40960
  a.syncv = ws + 112896;        // 1024
  a.scp   = ws + 113920;        // 4096
  a.cstat = ws + 118016;        // 512
  a.bar   = (unsigned*)(ws + 118528);  // 1024 uints

  k_init<<<1, 1024, 0, stream>>>(a.bar);
  k_mega<<<NBLK, NTHR, 0, stream>>>(a);
}

// Round 9
// 194.221 us; speedup vs baseline: 14.1717x; 1.0192x over previous
//
#include <hip/hip_runtime.h>

#define N_ 4096
#define M_ 10
#define T_ 10
#define B_ 1024
#define P_ 1024
#define NBLK 256
#define NTHR 512

__device__ __forceinline__ float wave_red_sum(float v) {
#pragma unroll
  for (int m = 32; m >= 1; m >>= 1) v += __shfl_xor(v, m);
  return v;
}

// Agent-scope bypass accessors (coherence-point served; no cache maintenance).
__device__ __forceinline__ float gld(const float* p) {
  return __hip_atomic_load(p, __ATOMIC_RELAXED, __HIP_MEMORY_SCOPE_AGENT);
}
__device__ __forceinline__ void gst(float* p, float v) {
  __hip_atomic_store(p, v, __ATOMIC_RELAXED, __HIP_MEMORY_SCOPE_AGENT);
}
__device__ __forceinline__ unsigned ld_u(unsigned* p) {
  return __hip_atomic_load(p, __ATOMIC_RELAXED, __HIP_MEMORY_SCOPE_AGENT);
}

// Drain this block's bypass stores (per-wave vmcnt, then block barrier).
__device__ __forceinline__ void drain_sync() {
  asm volatile("s_waitcnt vmcnt(0)" ::: "memory");
  __syncthreads();
}
// Signal: one plain bypass store (call after drain_sync). No atomics.
__device__ __forceinline__ void signal(unsigned* slot, unsigned val) {
  if (threadIdx.x == 0)
    __hip_atomic_store(slot, val, __ATOMIC_RELAXED, __HIP_MEMORY_SCOPE_AGENT);
}
// Wait until slots[0..n) all >= target. Wave 0 scans; __all over 64 lanes.
__device__ __forceinline__ void wait_set(unsigned* slots, int n, unsigned target) {
  if (threadIdx.x < 64) {
    int lane = threadIdx.x;
    bool ok;
    do {
      ok = true;
      for (int i = lane; i < n; i += 64) ok &= (ld_u(&slots[i]) >= target);
      ok = __all(ok);
      if (!ok) __builtin_amdgcn_s_sleep(1);
    } while (!ok);
  }
  __syncthreads();
}
// Wait until slots[s + 8*i] >= target for i in [0,32) (strip's producers).
__device__ __forceinline__ void wait_mod8(unsigned* slots, int s, unsigned target) {
  if (threadIdx.x < 64) {
    int lane = threadIdx.x;
    bool ok;
    do {
      ok = (lane < 32) ? (ld_u(&slots[s + 8 * lane]) >= target) : true;
      ok = __all(ok);
      if (!ok) __builtin_amdgcn_s_sleep(1);
    } while (!ok);
  }
  __syncthreads();
}

__global__ void k_init(unsigned* __restrict__ bar) {
  if (threadIdx.x < 1024)
    __hip_atomic_store(bar + threadIdx.x, 0u, __ATOMIC_RELAXED, __HIP_MEMORY_SCOPE_AGENT);
}

struct MArgs {
  const float *x, *post0, *pre0;
  const int* pairs;
  const float* decay;
  const float *iew1, *ieb1, *ieg1, *iebe1, *iew2, *ieb2, *ieg2, *iebe2, *iew3, *ieb3;
  const float *syw1, *syb1, *syg, *sybe, *syw2, *syb2;
  const float *nw1, *nb1, *ng, *nbe, *nw2, *nb2;
  const float *vw, *vb;
  const float *rdw1, *rdb1, *rdg1, *rdbe1, *rdw2, *rdb2, *rdg2, *rdbe2, *rdw3, *rdb3;
  float *pc, *pc2, *enc_g, *hbar, *postG, *scp;
  float* out;
  unsigned* bar;
};

// ONE persistent mega-kernel. 256 blocks x 512 threads, 1 block/CU.
// Block g: neurons [16g,16g+16) (nm_w1/syw1 pinned in LDS), batch rows [4g,4g+4)
// (encoder + readout), ONE hbar column (j = g).
// Tick: slotA(all) -> strips(mod-8) -> slotR -> all{cval,stats,mb/rb,own col} ->
// slotC -> all{npre,nm,pc}. 3 hops/tick; plain-store signaling, monotonic slots.
__global__ __launch_bounds__(NTHR)
void k_mega(MArgs a) {
  const int g = blockIdx.x, tid = threadIdx.x;
  const int lane = tid & 63;
  const int n0 = g * 16, b0e = g * 4;

  __shared__ float s_w1[16 * M_ * 128];   // 80 KB nm_w1 slice
  __shared__ float s_syw1[16 * 256];      // 16 KB sy_w1 rows 4+n0..
  __shared__ float s_w4[4 * 256];         // 4 KB sy_w1 rows 0..3
  __shared__ float reg1[4096];            // fx | encT | r1+p2
  __shared__ float reg2[1024];            // e1/e2/encs | r2
  __shared__ float s_mbrb[2048];          // mb[1024], rb[1024]
  __shared__ float s_values[4][64];
  __shared__ float s_post[16][M_];
  __shared__ float s_pre[16][M_];
  __shared__ float s_pl[16];
  __shared__ float s_hbar[256];
  __shared__ float s_cval[256];
  __shared__ float s_tmp[2][256];
  __shared__ float s_stats[20];           // [0..5] tick, [6..19] static

  unsigned* slotA = a.bar;          // 256 words, one per block
  unsigned* slotR = a.bar + 256;    // 8 words (strips)
  unsigned* slotC = a.bar + 320;    // 256 words (hbar columns)

  // ================= PROLOGUE ===============================================
  {
    const float4* src = (const float4*)(a.nw1 + n0 * M_ * 128);
    float4* dst = (float4*)s_w1;
    for (int i = tid; i < 16 * M_ * 128 / 4; i += NTHR) dst[i] = src[i];
    const float4* s2 = (const float4*)(a.syw1 + (4 + n0) * 256);
    float4* d2 = (float4*)s_syw1;
    for (int i = tid; i < 16 * 256 / 4; i += NTHR) d2[i] = s2[i];
    const float4* s3 = (const float4*)a.syw1;
    float4* d3 = (float4*)s_w4;
    for (int i = tid; i < 1024 / 4; i += NTHR) d3[i] = s3[i];
    if (tid < 160) {
      int r = tid / 10, m = tid - r * 10;
      s_post[r][m] = a.post0[(n0 + r) * M_ + m];
      s_pre[r][m]  = a.pre0[(n0 + r) * M_ + m];
    }
    for (int i = tid; i < 4 * 784; i += NTHR) reg1[i] = a.x[b0e * 784 + i];
  }
  __syncthreads();
  if (tid < 16) s_pl[tid] = s_post[tid][M_ - 1];

  {  // encoder E1: 4 rows x 128 j
    int r = tid >> 7, j = tid & 127;
    float u = a.ieb1[j];
    const float* fxr = reg1 + r * 784;
    for (int k = 0; k < 784; ++k) u += fxr[k] * a.iew1[k * 128 + j];
    float s = wave_red_sum(u), sq = wave_red_sum(u * u);
    int w = tid >> 6;
    if (lane == 0) { s_tmp[0][w] = s; s_tmp[1][w] = sq; }
    __syncthreads();
    float S = s_tmp[0][r * 2] + s_tmp[0][r * 2 + 1];
    float S2 = s_tmp[1][r * 2] + s_tmp[1][r * 2 + 1];
    float mm = S * (1.f / 128.f), vv = S2 * (1.f / 128.f) - mm * mm;
    reg2[r * 128 + j] = fmaxf((u - mm) * rsqrtf(vv + 1e-5f) * a.ieg1[j] + a.iebe1[j], 0.f);
  }
  __syncthreads();
  if (tid < 128) {  // E2: 4 rows x 32, LN32 via width-32 shuffles
    int r = tid >> 5, jj = tid & 31;
    float u = a.ieb2[jj];
    for (int k = 0; k < 128; ++k) u += reg2[r * 128 + k] * a.iew2[k * 32 + jj];
    float ss = u, sq = u * u;
#pragma unroll
    for (int m = 16; m >= 1; m >>= 1) { ss += __shfl_xor(ss, m, 32); sq += __shfl_xor(sq, m, 32); }
    float mm = ss * (1.f / 32.f), vv = sq * (1.f / 32.f) - mm * mm;
    reg2[512 + r * 32 + jj] = fmaxf((u - mm) * rsqrtf(vv + 1e-5f) * a.ieg2[jj] + a.iebe2[jj], 0.f);
  }
  __syncthreads();
  if (tid < 16) {  // enc 4x4
    int r = tid >> 2, o = tid & 3;
    float u = a.ieb3[o];
    for (int k = 0; k < 32; ++k) u += reg2[512 + r * 32 + k] * a.iew3[k * 4 + o];
    reg2[640 + r * 4 + o] = u;
    gst(&a.enc_g[(b0e + r) * 4 + o], u);
  }
  __syncthreads();
  if (tid < 256) {  // values (softmax over size-1 axis == 1 -> att == values)
    int r = tid >> 6, v = tid & 63;
    float u = a.vb[v];
#pragma unroll
    for (int o = 0; o < 4; ++o) u += reg2[640 + r * 4 + o] * a.vw[o * 64 + v];
    s_values[r][v] = u;
  }
  __syncthreads();
  {  // first pc partial (pinned syw1)
    int j = tid & 255, half = tid >> 8;
    float acc = 0.f;
#pragma unroll
    for (int r = 0; r < 8; ++r) {
      int n = half * 8 + r;
      acc += s_pl[n] * s_syw1[n * 256 + j];
    }
    s_tmp[half][j] = acc;
  }
  __syncthreads();
  if (tid < 256) gst(&a.pc[g * 256 + tid], s_tmp[0][tid] + s_tmp[1][tid]);
  drain_sync();
  signal(&slotA[g], 1u);

  {  // static w4 moments (block-local, overlaps hop propagation)
    float q[14];
    if (tid < 256) {
      float wv[4] = {s_w4[tid], s_w4[256 + tid], s_w4[512 + tid], s_w4[768 + tid]};
      int idx = 0;
#pragma unroll
      for (int o = 0; o < 4; ++o) q[idx++] = wv[o];
#pragma unroll
      for (int o = 0; o < 4; ++o)
#pragma unroll
        for (int p = 0; p <= o; ++p) q[idx++] = wv[o] * wv[p];
    } else {
#pragma unroll
      for (int i = 0; i < 14; ++i) q[i] = 0.f;
    }
#pragma unroll
    for (int i = 0; i < 14; ++i) q[i] = wave_red_sum(q[i]);
    int w = tid >> 6;
    if (lane == 0) {
#pragma unroll
      for (int i = 0; i < 14; ++i) s_tmp[1][w * 16 + i] = q[i];
    }
    __syncthreads();
    if (tid < 14) {
      float S = 0.f;
#pragma unroll
      for (int w2 = 0; w2 < 8; ++w2) S += s_tmp[1][w2 * 16 + tid];
      s_stats[6 + tid] = S * (1.f / 256.f);
    }
  }
  __syncthreads();

  // ================= TICK LOOP ==============================================
  for (int t = 0; t < T_; ++t) {
    // strips: block s<8 reduces pc rows r = s + 8i -> pc2[s][256]
    if (g < 8) {
      wait_mod8(slotA, g, (unsigned)(t + 1));
      int j = tid & 255, half = tid >> 8;
      float acc = 0.f;
#pragma unroll
      for (int i = 0; i < 16; ++i) {
        int r = g + 8 * (half * 16 + i);
        acc += gld(&a.pc[r * 256 + j]);
      }
      s_tmp[half][j] = acc;
      __syncthreads();
      if (tid < 256) gst(&a.pc2[g * 256 + tid], s_tmp[0][tid] + s_tmp[1][tid]);
      drain_sync();
      signal(&slotR[g], (unsigned)(t + 1));
    }
    // everyone: cval + tick stats + mb/rb + own hbar column
    wait_set(slotR, 8, (unsigned)(t + 1));
    if (t == 0) {  // fill encT[4][1024] once
      for (int i = tid; i < 4096; i += NTHR) {
        int b = i >> 2, o = i & 3;
        reg1[o * 1024 + b] = gld(&a.enc_g[i]);
      }
    }
    {
      float cv = 0.f;
      if (tid < 256) {
        cv = a.syb1[tid];
#pragma unroll
        for (int s = 0; s < 8; ++s) cv += gld(&a.pc2[s * 256 + tid]);
        s_cval[tid] = cv;
      }
      // tick stats: mc, mcc, mcw[4]
      float p[6];
      if (tid < 256) {
        p[0] = cv; p[1] = cv * cv;
        p[2] = cv * s_w4[tid]; p[3] = cv * s_w4[256 + tid];
        p[4] = cv * s_w4[512 + tid]; p[5] = cv * s_w4[768 + tid];
      } else {
#pragma unroll
        for (int i = 0; i < 6; ++i) p[i] = 0.f;
      }
#pragma unroll
      for (int i = 0; i < 6; ++i) p[i] = wave_red_sum(p[i]);
      int w = tid >> 6;
      if (lane == 0) {
#pragma unroll
        for (int i = 0; i < 6; ++i) s_tmp[0][w * 8 + i] = p[i];
      }
      __syncthreads();
      if (tid < 6) {
        float S = 0.f;
#pragma unroll
        for (int w2 = 0; w2 < 8; ++w2) S += s_tmp[0][w2 * 8 + tid];
        s_stats[tid] = S * (1.f / 256.f);
      }
      __syncthreads();
    }
    {  // mb/rb for all 1024 b (2 per thread)
#pragma unroll
      for (int h2 = 0; h2 < 2; ++h2) {
        int b = h2 * 512 + tid;
        float e0 = reg1[b], e1v = reg1[1024 + b], e2v = reg1[2048 + b], e3v = reg1[3072 + b];
        float m = s_stats[0] + e0 * s_stats[6] + e1v * s_stats[7] + e2v * s_stats[8] + e3v * s_stats[9];
        float eu2 = s_stats[1] + 2.f * (e0 * s_stats[2] + e1v * s_stats[3] + e2v * s_stats[4] + e3v * s_stats[5]);
        float qf = e0 * e0 * s_stats[10]
                 + 2.f * e1v * e0 * s_stats[11] + e1v * e1v * s_stats[12]
                 + 2.f * e2v * e0 * s_stats[13] + 2.f * e2v * e1v * s_stats[14] + e2v * e2v * s_stats[15]
                 + 2.f * e3v * e0 * s_stats[16] + 2.f * e3v * e1v * s_stats[17]
                 + 2.f * e3v * e2v * s_stats[18] + e3v * e3v * s_stats[19];
        eu2 += qf;
        s_mbrb[b] = m;
        s_mbrb[1024 + b] = rsqrtf(eu2 - m * m + 1e-5f);
      }
      __syncthreads();
    }
    {  // own hbar column j = g: 2 b per thread, block reduction
      float cj = s_cval[g];
      float w0 = s_w4[g], w1v = s_w4[256 + g], w2v = s_w4[512 + g], w3v = s_w4[768 + g];
      float gj = a.syg[g], bj = a.sybe[g];
      float acc = 0.f;
#pragma unroll
      for (int h2 = 0; h2 < 2; ++h2) {
        int b = h2 * 512 + tid;
        float u = cj + reg1[b] * w0 + reg1[1024 + b] * w1v + reg1[2048 + b] * w2v + reg1[3072 + b] * w3v;
        float y = (u - s_mbrb[b]) * s_mbrb[1024 + b] * gj + bj;
        acc += fmaxf(y, 0.f);
      }
      acc = wave_red_sum(acc);
      int w = tid >> 6;
      if (lane == 0) s_tmp[0][w] = acc;
      __syncthreads();
      if (tid == 0) {
        float S = 0.f;
#pragma unroll
        for (int w2 = 0; w2 < 8; ++w2) S += s_tmp[0][w2];
        gst(&a.hbar[g], S * (1.f / 1024.f));
      }
    }
    drain_sync();
    signal(&slotC[g], (unsigned)(t + 1));
    // everyone: wait full hbar, then P3
    wait_set(slotC, 256, (unsigned)(t + 1));
    if (tid < 256) s_hbar[tid] = gld(&a.hbar[tid]);
    __syncthreads();
    {  // npre: s_tmp as [32][16]
      int nl = tid & 15, kq = tid >> 4;
      float u = 0.f;
#pragma unroll
      for (int kk = 0; kk < 8; ++kk) {
        int k = kq * 8 + kk;
        u += s_hbar[k] * a.syw2[k * N_ + n0 + nl];
      }
      ((float*)s_tmp)[kq * 16 + nl] = u;
    }
    __syncthreads();
    if (tid < 16) {
      float v = a.syb2[n0 + tid];
#pragma unroll
      for (int q2 = 0; q2 < 32; ++q2) v += ((float*)s_tmp)[q2 * 16 + tid];
#pragma unroll
      for (int m = 0; m < M_ - 1; ++m) s_pre[tid][m] = s_pre[tid][m + 1];
      s_pre[tid][M_ - 1] = v;
    }
    __syncthreads();
    {  // nm one-pass: 16 neurons x 32 lanes, LN via width-32 shuffles
      int nl = tid >> 5, q = tid & 31;
      int n2 = n0 + nl;
      float pr[M_];
#pragma unroll
      for (int m = 0; m < M_; ++m) pr[m] = s_pre[nl][m];
      float u[4];
#pragma unroll
      for (int k = 0; k < 4; ++k) {
        int j = q + 32 * k;
        float uu = a.nb1[n2 * 128 + j];
#pragma unroll
        for (int m = 0; m < M_; ++m) uu += pr[m] * s_w1[(nl * M_ + m) * 128 + j];
        u[k] = uu;
      }
      float s = u[0] + u[1] + u[2] + u[3];
      float sq = u[0] * u[0] + u[1] * u[1] + u[2] * u[2] + u[3] * u[3];
#pragma unroll
      for (int m = 16; m >= 1; m >>= 1) { s += __shfl_xor(s, m, 32); sq += __shfl_xor(sq, m, 32); }
      float mm = s * (1.f / 128.f), vv = sq * (1.f / 128.f) - mm * mm;
      float ri = rsqrtf(vv + 1e-5f);
      float d = 0.f;
#pragma unroll
      for (int k = 0; k < 4; ++k) {
        int j = q + 32 * k;
        float y = fmaxf((u[k] - mm) * ri * a.ng[n2 * 128 + j] + a.nbe[n2 * 128 + j], 0.f);
        d += y * a.nw2[n2 * 128 + j];
      }
#pragma unroll
      for (int m = 16; m >= 1; m >>= 1) d += __shfl_xor(d, m, 32);
      if (q == 0) {
        float npost = d + a.nb2[n2];
#pragma unroll
        for (int m = 0; m < M_ - 1; ++m) s_post[nl][m] = s_post[nl][m + 1];
        s_post[nl][M_ - 1] = npost;
        s_pl[nl] = npost;
      }
    }
    __syncthreads();
    if (t < T_ - 1) {  // next pc partial
      int j = tid & 255, half = tid >> 8;
      float acc = 0.f;
#pragma unroll
      for (int r = 0; r < 8; ++r) {
        int n = half * 8 + r;
        acc += s_pl[n] * s_syw1[n * 256 + j];
      }
      s_tmp[half][j] = acc;
      __syncthreads();
      if (tid < 256) gst(&a.pc[g * 256 + tid], s_tmp[0][tid] + s_tmp[1][tid]);
    } else {  // flush final post rows
      if (tid < 160) {
        int r = tid / 10, m = tid - r * 10;
        gst(&a.postG[(n0 + r) * M_ + m], s_post[r][m]);
      }
    }
    drain_sync();
    signal(&slotA[g], (unsigned)(t + 2));
  }

  // ================= EPILOGUE ===============================================
  // strips: syncv (own 128 pairs) + scp partial in one stage
  if (g < 8) {
    wait_set(slotA, 256, 11u);
    if (tid < 128) {
      int p = g * 128 + tid;
      int i = a.pairs[p * 2], jn = a.pairs[p * 2 + 1];
      float dc = a.decay[p];
      float num = 0.f, den = 0.f;
#pragma unroll
      for (int l = 0; l < M_; ++l) {
        float r = expf(-dc * (float)(M_ - 1 - l));
        num += gld(&a.postG[i * M_ + l]) * r * gld(&a.postG[jn * M_ + l]);
        den += r;
      }
      s_tmp[0][tid] = num / (den + 1e-8f);
    }
    __syncthreads();
    float acc = 0.f;
    for (int i = 0; i < 128; ++i)
      acc += s_tmp[0][i] * a.rdw1[(64 + g * 128 + i) * 512 + tid];
    gst(&a.scp[g * 512 + tid], acc);
    drain_sync();
    signal(&slotR[g], 11u);
  }
  wait_set(slotR, 8, 11u);
  {  // readout for own 4 batch rows
    float* r1 = reg1;
    float* p2 = reg1 + 2048;
    float base = a.rdb1[tid];
#pragma unroll
    for (int s = 0; s < 8; ++s) base += gld(&a.scp[s * 512 + tid]);
    float u[4];
#pragma unroll
    for (int r = 0; r < 4; ++r) u[r] = base;
    for (int k = 0; k < 64; ++k) {
      float w = a.rdw1[k * 512 + tid];
#pragma unroll
      for (int r = 0; r < 4; ++r) u[r] += s_values[r][k] * w;
    }
    int wid = tid >> 6;
#pragma unroll
    for (int r = 0; r < 4; ++r) {
      float s = wave_red_sum(u[r]), sq = wave_red_sum(u[r] * u[r]);
      if (lane == 0) { s_tmp[0][r * 8 + wid] = s; s_tmp[1][r * 8 + wid] = sq; }
    }
    __syncthreads();
    float gg = a.rdg1[tid], bb = a.rdbe1[tid];
#pragma unroll
    for (int r = 0; r < 4; ++r) {
      float S = 0.f, S2 = 0.f;
#pragma unroll
      for (int w = 0; w < 8; ++w) { S += s_tmp[0][r * 8 + w]; S2 += s_tmp[1][r * 8 + w]; }
      float m = S * (1.f / 512.f), v = S2 * (1.f / 512.f) - m * m;
      r1[r * 512 + tid] = fmaxf((u[r] - m) * rsqrtf(v + 1e-5f) * gg + bb, 0.f);
    }
    __syncthreads();
    int o = tid & 63, kq = tid >> 6;
    float u2[4] = {0.f, 0.f, 0.f, 0.f};
#pragma unroll
    for (int kk = 0; kk < 64; ++kk) {
      int k = kq * 64 + kk;
      float w = a.rdw2[k * 64 + o];
#pragma unroll
      for (int r = 0; r < 4; ++r) u2[r] += r1[r * 512 + k] * w;
    }
#pragma unroll
    for (int r = 0; r < 4; ++r) p2[(kq * 4 + r) * 64 + o] = u2[r];
    __syncthreads();
    if (tid < 256) {
      int r = tid >> 6, o2 = tid & 63;
      float v = a.rdb2[o2];
#pragma unroll
      for (int q = 0; q < 8; ++q) v += p2[(q * 4 + r) * 64 + o2];
      float s = wave_red_sum(v), sq = wave_red_sum(v * v);
      float m = s * (1.f / 64.f), var = sq * (1.f / 64.f) - m * m;
      reg2[r * 64 + o2] = fmaxf((v - m) * rsqrtf(var + 1e-5f) * a.rdg2[o2] + a.rdbe2[o2], 0.f);
    }
    __syncthreads();
    if (tid < 40) {
      int r = tid / 10, o3 = tid - r * 10;
      float acc = a.rdb3[o3];
#pragma unroll
      for (int k = 0; k < 64; ++k) acc += reg2[r * 64 + k] * a.rdw3[k * 10 + o3];
      a.out[(b0e + r) * 10 + o3] = acc;
    }
  }
}

extern "C" void kernel_launch(void* const* d_in, const int* in_sizes, int n_in,
                              void* d_out, int out_size, void* d_ws, size_t ws_size,
                              hipStream_t stream) {
  MArgs a;
  a.x     = (const float*)d_in[0];
  a.post0 = (const float*)d_in[1];
  a.pre0  = (const float*)d_in[2];
  a.pairs = (const int*)d_in[3];
  a.decay = (const float*)d_in[4];
  a.iew1  = (const float*)d_in[5];
  a.ieb1  = (const float*)d_in[6];
  a.ieg1  = (const float*)d_in[7];
  a.iebe1 = (const float*)d_in[8];
  a.iew2  = (const float*)d_in[9];
  a.ieb2  = (const float*)d_in[10];
  a.ieg2  = (const float*)d_in[11];
  a.iebe2 = (const float*)d_in[12];
  a.iew3  = (const float*)d_in[13];
  a.ieb3  = (const float*)d_in[14];
  a.syw1  = (const float*)d_in[15];
  a.syb1  = (const float*)d_in[16];
  a.syg   = (const float*)d_in[17];
  a.sybe  = (const float*)d_in[18];
  a.syw2  = (const float*)d_in[19];
  a.syb2  = (const float*)d_in[20];
  a.nw1   = (const float*)d_in[21];
  a.nb1   = (const float*)d_in[22];
  a.ng    = (const float*)d_in[23];
  a.nbe   = (const float*)d_in[24];
  a.nw2   = (const float*)d_in[25];
  a.nb2   = (const float*)d_in[26];
  a.vw    = (const float*)d_in[29];
  a.vb    = (const float*)d_in[30];
  a.rdw1  = (const float*)d_in[33];
  a.rdb1  = (const float*)d_in[34];
  a.rdg1  = (const float*)d_in[35];
  a.rdbe1 = (const float*)d_in[36];
  a.rdw2  = (const float*)d_in[37];
  a.rdb2  = (const float*)d_in[38];
  a.rdg2  = (const float*)d_in[39];
  a.rdbe2 = (const float*)d_in[40];
  a.rdw3  = (const float*)d_in[41];
  a.rdb3  = (const float*)d_in[42];
  a.out = (float*)d_out;

  float* ws = (float*)d_ws;
  a.pc    = ws;                 // 65536
  a.pc2   = ws + 65536;         // 2048
  a.enc_g = ws + 67584;         // 4096
  a.hbar  = ws + 71680;         // 256
  a.postG = ws + 71936;         // 40960
  a.scp   = ws + 112896;        // 4096
  a.bar   = (unsigned*)(ws + 117000);  // 1024 uints

  k_init<<<1, 1024, 0, stream>>>(a.bar);
  k_mega<<<NBLK, NTHR, 0, stream>>>(a);
}